// Round 1
// baseline (760.438 us; speedup 1.0000x reference)
//
#include <hip/hip_runtime.h>

// ---------------------------------------------------------------------------
// Problem geometry (fixed):
//  b=64, units=32, d_model=4096, P=16 -> c=2, d=256, C=512 channels,
//  dwconv 3x3 s2: 16x16 -> 8x8 (hw=64), dk=64.
//  attention per (b,cc): 256x256 over dk=64.
//  conv1d: 16->32 over l=2048; linear: 2048->4096.
// Workspace layout (bytes):
//   tT   [3][64][64][512] f32 @ 0         (25165824 B)  dead after pointwise
//   u    [3][64][512][64] f32 @ 25165824  (25165824 B)  dead after attention
//   xatt [64][2][256][64] f32 @ 0         ( 8388608 B)  reuses tT region
//   y1   [64][32][2048]   f32 @ 8388608   (16777216 B)  reuses tT region
// Total ws needed: 50331648 B.
// ---------------------------------------------------------------------------

// ======================= Stage A: patch + dwconv + BN + GELU ================
// One thread per output element; writes transposed layout tT[i][b][hw][ch]
// so the pointwise conv becomes an NT GEMM with B rows contiguous in K.
__global__ __launch_bounds__(256) void stageA_kernel(
    const float* __restrict__ q, const float* __restrict__ k,
    const float* __restrict__ v, const float* __restrict__ dwk,
    const float* __restrict__ bng, const float* __restrict__ bnb,
    const float* __restrict__ bnm, const float* __restrict__ bnv,
    float* __restrict__ tT)
{
  int idx = blockIdx.x * 256 + threadIdx.x;   // total 3*64*64*512 = 6291456
  int ch = idx & 511;
  int hw = (idx >> 9) & 63;
  int b  = (idx >> 15) & 63;
  int i  = idx >> 21;                          // 0..2
  const float* x = (i == 0) ? q : (i == 1) ? k : v;
  int cc = ch >> 8, dd = ch & 255;
  int oh = hw >> 3, ow = hw & 7;
  const float* wp = dwk + (size_t)(i * 512 + ch) * 9;
  float acc = 0.f;
#pragma unroll
  for (int kh = 0; kh < 3; ++kh) {
    int ih = 2 * oh - 1 + kh;
    if (ih < 0 || ih > 15) continue;
#pragma unroll
    for (int kw = 0; kw < 3; ++kw) {
      int iw = 2 * ow - 1 + kw;
      if (iw < 0 || iw > 15) continue;
      acc += x[(size_t)(b * 32 + cc * 16 + ih) * 4096 + dd * 16 + iw] * wp[kh * 3 + kw];
    }
  }
  int pc = i * 512 + ch;
  float y = (acc - bnm[pc]) * (bng[pc] / sqrtf(bnv[pc] + 1e-5f)) + bnb[pc];
  y = 0.5f * y * (1.f + erff(y * 0.70710678118654752f));   // exact-erf GELU
  tT[(((size_t)i * 64 + b) * 64 + hw) * 512 + ch] = y;
}

// ======================= Generic fp32 NT GEMM ==============================
// C[M,N] = A[M,K] (row-major) * B[N,K]^T (row-major), 128x128 tile, BK=16,
// 256 threads, 8x8 per thread (split 4+4 with 64 offset).
// mode 0: C = Call + m*N + n  (+ bias[n])           (final linear)
// mode 1: store u[z][b][o][hw]: n=(b*64+hw), m=o     (pointwise conv)
#define BM 128
#define BN 128
#define BKK 16

__global__ __launch_bounds__(256) void gemm_nt_kernel(
    const float* __restrict__ Aall, const float* __restrict__ Ball,
    float* __restrict__ Call, const float* __restrict__ bias,
    int M, int N, int K, int mode)
{
  __shared__ float As[BKK][BM + 4];
  __shared__ float Bs[BKK][BN + 4];
  const int t = threadIdx.x;
  const int tx = t & 15, ty = t >> 4;
  const int m0 = blockIdx.y * BM, n0 = blockIdx.x * BN;
  const int z = blockIdx.z;
  const float* A = Aall + (size_t)z * M * K;
  const float* Bm = Ball + (size_t)z * N * K;

  float acc[8][8];
#pragma unroll
  for (int i2 = 0; i2 < 8; ++i2)
#pragma unroll
    for (int j = 0; j < 8; ++j) acc[i2][j] = 0.f;

  const int lr = t >> 1;            // 0..127 row within tile
  const int lk = (t & 1) * 8;       // 0 or 8

  for (int k0 = 0; k0 < K; k0 += BKK) {
    const float4 a0 = *(const float4*)(A + (size_t)(m0 + lr) * K + k0 + lk);
    const float4 a1 = *(const float4*)(A + (size_t)(m0 + lr) * K + k0 + lk + 4);
    const float4 b0 = *(const float4*)(Bm + (size_t)(n0 + lr) * K + k0 + lk);
    const float4 b1 = *(const float4*)(Bm + (size_t)(n0 + lr) * K + k0 + lk + 4);
    __syncthreads();
    As[lk + 0][lr] = a0.x; As[lk + 1][lr] = a0.y; As[lk + 2][lr] = a0.z; As[lk + 3][lr] = a0.w;
    As[lk + 4][lr] = a1.x; As[lk + 5][lr] = a1.y; As[lk + 6][lr] = a1.z; As[lk + 7][lr] = a1.w;
    Bs[lk + 0][lr] = b0.x; Bs[lk + 1][lr] = b0.y; Bs[lk + 2][lr] = b0.z; Bs[lk + 3][lr] = b0.w;
    Bs[lk + 4][lr] = b1.x; Bs[lk + 5][lr] = b1.y; Bs[lk + 6][lr] = b1.z; Bs[lk + 7][lr] = b1.w;
    __syncthreads();
#pragma unroll
    for (int kk = 0; kk < BKK; ++kk) {
      float a[8], bb[8];
      *(float4*)&a[0]  = *(const float4*)&As[kk][ty * 4];
      *(float4*)&a[4]  = *(const float4*)&As[kk][64 + ty * 4];
      *(float4*)&bb[0] = *(const float4*)&Bs[kk][tx * 4];
      *(float4*)&bb[4] = *(const float4*)&Bs[kk][64 + tx * 4];
#pragma unroll
      for (int i2 = 0; i2 < 8; ++i2)
#pragma unroll
        for (int j = 0; j < 8; ++j)
          acc[i2][j] = fmaf(a[i2], bb[j], acc[i2][j]);
    }
  }

  if (mode == 0) {
#pragma unroll
    for (int i2 = 0; i2 < 8; ++i2) {
      int m = m0 + ((i2 >> 2) * 64) + ty * 4 + (i2 & 3);
#pragma unroll
      for (int jh = 0; jh < 2; ++jh) {
        int n = n0 + jh * 64 + tx * 4;
        float4 vv;
        vv.x = acc[i2][jh * 4 + 0] + (bias ? bias[n + 0] : 0.f);
        vv.y = acc[i2][jh * 4 + 1] + (bias ? bias[n + 1] : 0.f);
        vv.z = acc[i2][jh * 4 + 2] + (bias ? bias[n + 2] : 0.f);
        vv.w = acc[i2][jh * 4 + 3] + (bias ? bias[n + 3] : 0.f);
        *(float4*)(Call + (size_t)m * N + n) = vv;
      }
    }
  } else {
    float* Cz = Call + (size_t)z * 64 * 512 * 64;
#pragma unroll
    for (int i2 = 0; i2 < 8; ++i2) {
      int m = m0 + ((i2 >> 2) * 64) + ty * 4 + (i2 & 3);   // o
#pragma unroll
      for (int jh = 0; jh < 2; ++jh) {
        int n = n0 + jh * 64 + tx * 4;                      // b*64 + hw
        int bidx = n >> 6, hw = n & 63;
        float4 vv;
        vv.x = acc[i2][jh * 4 + 0];
        vv.y = acc[i2][jh * 4 + 1];
        vv.z = acc[i2][jh * 4 + 2];
        vv.w = acc[i2][jh * 4 + 3];
        *(float4*)(Cz + ((size_t)bidx * 512 + m) * 64 + hw) = vv;
      }
    }
  }
}

// ======================= Attention =========================================
// Per block: (rt, cc, b) -> 32 query rows. K/V chunks of 64 staged in LDS.
// scores kept in LDS [32][260]; wave-local softmax (8 lanes / row).
__global__ __launch_bounds__(256) void attn_kernel(
    const float* __restrict__ u,     // [3][64][512][64]
    const float* __restrict__ pos,   // [2][256][256]
    float* __restrict__ xatt)        // [64][2][256][64]
{
  __shared__ float qs[32][68];
  __shared__ float ks[64][68];
  __shared__ float sc[32][260];
  const int t = threadIdx.x;
  const int rt = blockIdx.x;   // 0..7
  const int cc = blockIdx.y;   // 0..1
  const int b  = blockIdx.z;   // 0..63
  const int i0 = rt * 32;

  const float* Q  = u + ((size_t)(0 * 64 + b) * 512 + cc * 256) * 64;
  const float* Km = u + ((size_t)(1 * 64 + b) * 512 + cc * 256) * 64;
  const float* Vm = u + ((size_t)(2 * 64 + b) * 512 + cc * 256) * 64;

  // stage Q tile: 32 rows x 64
#pragma unroll
  for (int rep = 0; rep < 2; ++rep) {
    int flat = t + rep * 256;          // 0..511
    int r = flat >> 4;                 // 0..31
    int kq = (flat & 15) * 4;
    float4 v4 = *(const float4*)(Q + (size_t)(i0 + r) * 64 + kq);
    *(float4*)&qs[r][kq] = v4;
  }

  const int rg = t >> 4;       // 0..15 -> rows {2rg, 2rg+1}
  const int cg = t & 15;       // cols {cg + 16*jj}
  const int rg2 = rg * 2;

  // -------- scores --------
  for (int chunk = 0; chunk < 4; ++chunk) {
    __syncthreads();
#pragma unroll
    for (int rep = 0; rep < 4; ++rep) {
      int flat = t + rep * 256;        // 0..1023
      int jr = flat >> 4; int kq = (flat & 15) * 4;
      float4 v4 = *(const float4*)(Km + (size_t)(chunk * 64 + jr) * 64 + kq);
      *(float4*)&ks[jr][kq] = v4;
    }
    __syncthreads();

    float d2[2][4];
#pragma unroll
    for (int rr = 0; rr < 2; ++rr)
#pragma unroll
      for (int jj = 0; jj < 4; ++jj) d2[rr][jj] = 0.f;

    for (int k4 = 0; k4 < 64; k4 += 4) {
      float4 a0 = *(const float4*)&qs[rg2][k4];
      float4 a1 = *(const float4*)&qs[rg2 + 1][k4];
#pragma unroll
      for (int jj = 0; jj < 4; ++jj) {
        float4 bv = *(const float4*)&ks[cg + 16 * jj][k4];
        d2[0][jj] = fmaf(a0.x, bv.x, fmaf(a0.y, bv.y, fmaf(a0.z, bv.z, fmaf(a0.w, bv.w, d2[0][jj]))));
        d2[1][jj] = fmaf(a1.x, bv.x, fmaf(a1.y, bv.y, fmaf(a1.z, bv.z, fmaf(a1.w, bv.w, d2[1][jj]))));
      }
    }
#pragma unroll
    for (int rr = 0; rr < 2; ++rr)
#pragma unroll
      for (int jj = 0; jj < 4; ++jj) {
        int j = chunk * 64 + cg + 16 * jj;
        int ig = i0 + rg2 + rr;
        sc[rg2 + rr][j] = d2[rr][jj] * 0.125f + pos[((size_t)cc * 256 + ig) * 256 + j];
      }
  }
  __syncthreads();

  // -------- softmax (8 lanes per row, wave-local) --------
  {
    const int r = t >> 3;      // 0..31
    const int j8 = t & 7;
    float mx = -3.4e38f;
#pragma unroll
    for (int jj = 0; jj < 32; ++jj) mx = fmaxf(mx, sc[r][j8 + 8 * jj]);
#pragma unroll
    for (int mset = 1; mset < 8; mset <<= 1) mx = fmaxf(mx, __shfl_xor(mx, mset, 64));
    float sum = 0.f;
#pragma unroll
    for (int jj = 0; jj < 32; ++jj) {
      float e = __expf(sc[r][j8 + 8 * jj] - mx);
      e = expf(sc[r][j8 + 8 * jj] - mx);   // exact expf for accuracy
      sc[r][j8 + 8 * jj] = e;
      sum += e;
    }
#pragma unroll
    for (int mset = 1; mset < 8; mset <<= 1) sum += __shfl_xor(sum, mset, 64);
    float inv = 1.f / sum;
#pragma unroll
    for (int jj = 0; jj < 32; ++jj) sc[r][j8 + 8 * jj] *= inv;
  }

  // -------- PV --------
  float oacc[2][4];
#pragma unroll
  for (int rr = 0; rr < 2; ++rr)
#pragma unroll
    for (int kk = 0; kk < 4; ++kk) oacc[rr][kk] = 0.f;

  for (int chunk = 0; chunk < 4; ++chunk) {
    __syncthreads();
#pragma unroll
    for (int rep = 0; rep < 4; ++rep) {
      int flat = t + rep * 256;
      int jr = flat >> 4; int kq = (flat & 15) * 4;
      float4 v4 = *(const float4*)(Vm + (size_t)(chunk * 64 + jr) * 64 + kq);
      *(float4*)&ks[jr][kq] = v4;
    }
    __syncthreads();
    for (int jl = 0; jl < 64; ++jl) {
      float p0 = sc[rg2][chunk * 64 + jl];
      float p1 = sc[rg2 + 1][chunk * 64 + jl];
#pragma unroll
      for (int kk = 0; kk < 4; ++kk) {
        float vv = ks[jl][cg + 16 * kk];
        oacc[0][kk] = fmaf(p0, vv, oacc[0][kk]);
        oacc[1][kk] = fmaf(p1, vv, oacc[1][kk]);
      }
    }
  }
#pragma unroll
  for (int rr = 0; rr < 2; ++rr) {
    float* O = xatt + ((size_t)(b * 2 + cc) * 256 + i0 + rg2 + rr) * 64;
#pragma unroll
    for (int kk = 0; kk < 4; ++kk) O[cg + 16 * kk] = oacc[rr][kk];
  }
}

// ======================= rearrange + conv1d ================================
// y1[b][o][l] = sum_ch X[b][ch][l] * c1w[o][ch] + c1b[o]
// X[b][cc*8+p1][dd*8+p2] = xatt[b][cc][dd][p1*8+p2]
__global__ __launch_bounds__(256) void conv1d_kernel(
    const float* __restrict__ xatt, const float* __restrict__ w,
    const float* __restrict__ bias, float* __restrict__ y1)
{
  int idx = blockIdx.x * 256 + threadIdx.x;  // total 64*32*2048 = 4194304
  int l = idx & 2047;
  int o = (idx >> 11) & 31;
  int b = idx >> 16;
  int dd = l >> 3, p2 = l & 7;
  float s = bias[o];
#pragma unroll
  for (int ch = 0; ch < 16; ++ch) {
    int ccc = ch >> 3, p1 = ch & 7;
    float xv = xatt[(((size_t)b * 2 + ccc) * 256 + dd) * 64 + p1 * 8 + p2];
    s = fmaf(xv, w[o * 16 + ch], s);
  }
  y1[idx] = s;   // == y1[(b*32+o)*2048 + l]
}

// ======================= launch ============================================
extern "C" void kernel_launch(void* const* d_in, const int* in_sizes, int n_in,
                              void* d_out, int out_size, void* d_ws, size_t ws_size,
                              hipStream_t stream) {
  const float* q    = (const float*)d_in[0];
  const float* k    = (const float*)d_in[1];
  const float* v    = (const float*)d_in[2];
  const float* dwk  = (const float*)d_in[3];
  const float* bng  = (const float*)d_in[4];
  const float* bnb  = (const float*)d_in[5];
  const float* bnm  = (const float*)d_in[6];
  const float* bnv  = (const float*)d_in[7];
  const float* pwk  = (const float*)d_in[8];
  const float* pos  = (const float*)d_in[9];
  const float* c1w  = (const float*)d_in[10];
  const float* c1b  = (const float*)d_in[11];
  const float* linw = (const float*)d_in[12];
  const float* linb = (const float*)d_in[13];
  float* out = (float*)d_out;

  if (ws_size < 50331648u) return;   // need 48 MiB of scratch

  char* ws = (char*)d_ws;
  float* tT   = (float*)(ws + 0);          // [3][64][64][512]
  float* u    = (float*)(ws + 25165824);   // [3][64][512][64]
  float* xatt = (float*)(ws + 0);          // [64][2][256][64]  (reuses tT)
  float* y1   = (float*)(ws + 8388608);    // [64][32][2048]    (reuses tT)

  stageA_kernel<<<24576, 256, 0, stream>>>(q, k, v, dwk, bng, bnb, bnm, bnv, tT);

  dim3 g1(32, 4, 3);   // N=4096/128, M=512/128, 3 inputs
  gemm_nt_kernel<<<g1, 256, 0, stream>>>(pwk, tT, u, nullptr, 512, 4096, 512, 1);

  dim3 g2(8, 2, 64);   // row tiles, cc, b
  attn_kernel<<<g2, 256, 0, stream>>>(u, pos, xatt);

  conv1d_kernel<<<16384, 256, 0, stream>>>(xatt, c1w, c1b, y1);

  dim3 g3(32, 16, 1);  // N=4096/128, M=2048/128
  gemm_nt_kernel<<<g3, 256, 0, stream>>>(y1, linw, out, linb, 2048, 4096, 2048, 0);
}

// Round 2
// 463.702 us; speedup vs baseline: 1.6399x; 1.6399x over previous
//
#include <hip/hip_runtime.h>

// ---------------------------------------------------------------------------
// Geometry: b=64, units=32, d_model=4096, P=16 -> c=2, d=256, C=512,
// dwconv 3x3 s2 16x16->8x8 (hw=64), dk=64; attn 256x256 per (b,cc);
// conv1d 16->32 over l=2048; linear 2048->4096.
//
// GEMMs run as bf16 hi/lo split MFMA:  C = Ah*Bh + Ah*Bl + Al*Bh  (K' = 3K),
// with A' stored [Ah|Al] ([M][2K] bf16) and B' stored [Bh|Bl] ([N][2K] bf16);
// the K'-segment -> stored-column remap happens in the staging addresses.
//
// Workspace (bytes), ws >= 50331648 (48 MiB exactly at peak):
//   phase1 (x3 loop): u fp32 [3][64][512][64] @ 0            (25,165,824)
//                     tT'_i bf16 [4096][1024] @ 25,165,824   (12,582,912)
//                     pwk'_i bf16 [512][1024] @ 37,748,736   ( 1,048,576)
//   phase2: xatt fp32 [64][2][256][64]        @ 25,165,824   ( 8,388,608)
//   phase3: y1' bf16 [2048][4096]             @ 0            (16,777,216)
//           linw' bf16 [4096][4096]           @ 16,777,216   (33,554,432)
// ---------------------------------------------------------------------------

typedef short s16x8 __attribute__((ext_vector_type(8)));
typedef float f32x4 __attribute__((ext_vector_type(4)));
typedef const __attribute__((address_space(1))) void* gas_t;
typedef __attribute__((address_space(3))) void* las_t;

__device__ __forceinline__ unsigned short f2bf(float x) {
  unsigned u = __float_as_uint(x);
  unsigned r = u + 0x7fffu + ((u >> 16) & 1u);
  return (unsigned short)(r >> 16);
}
__device__ __forceinline__ float bf2f(unsigned short h) {
  return __uint_as_float((unsigned)h << 16);
}

// ======================= Stage A: patch + dwconv + BN + GELU ===============
// One input (i) per launch; writes tT'_i bf16 [4096 rows=(b*64+hw)][1024=hi|lo]
__global__ __launch_bounds__(256) void stageA_kernel(
    const float* __restrict__ x, const float* __restrict__ dwk_i,
    const float* __restrict__ bng, const float* __restrict__ bnb,
    const float* __restrict__ bnm, const float* __restrict__ bnv,
    unsigned short* __restrict__ tTp)
{
  int idx = blockIdx.x * 256 + threadIdx.x;   // 64*64*512 = 2,097,152
  int ch = idx & 511;
  int hw = (idx >> 9) & 63;
  int b  = idx >> 15;
  int cc = ch >> 8, dd = ch & 255;
  int oh = hw >> 3, ow = hw & 7;
  const float* wp = dwk_i + (size_t)ch * 9;
  float acc = 0.f;
#pragma unroll
  for (int kh = 0; kh < 3; ++kh) {
    int ih = 2 * oh - 1 + kh;
    if (ih < 0 || ih > 15) continue;
#pragma unroll
    for (int kw = 0; kw < 3; ++kw) {
      int iw = 2 * ow - 1 + kw;
      if (iw < 0 || iw > 15) continue;
      acc += x[(size_t)(b * 32 + cc * 16 + ih) * 4096 + dd * 16 + iw] * wp[kh * 3 + kw];
    }
  }
  float y = (acc - bnm[ch]) * (bng[ch] / sqrtf(bnv[ch] + 1e-5f)) + bnb[ch];
  y = 0.5f * y * (1.f + erff(y * 0.70710678118654752f));
  unsigned short hi = f2bf(y);
  unsigned short lo = f2bf(y - bf2f(hi));
  size_t rowb = (size_t)(b * 64 + hw) * 1024;
  tTp[rowb + ch] = hi;
  tTp[rowb + 512 + ch] = lo;
}

// ======================= fp32 -> bf16 hi|lo split ==========================
// dst[r][c]=hi, dst[r][K+c]=lo ; K = 1<<kshift ; 4 elements per thread.
__global__ __launch_bounds__(256) void split_kernel(
    const float* __restrict__ src, unsigned short* __restrict__ dst,
    int kshift, int total4)
{
  int i = blockIdx.x * 256 + threadIdx.x;
  if (i >= total4) return;
  size_t i4 = (size_t)i * 4;
  int K = 1 << kshift;
  int r = (int)(i4 >> kshift);
  int c = (int)(i4 & (size_t)(K - 1));
  float4 xv = *(const float4*)(src + i4);
  unsigned short h0 = f2bf(xv.x), h1 = f2bf(xv.y), h2 = f2bf(xv.z), h3 = f2bf(xv.w);
  unsigned short l0 = f2bf(xv.x - bf2f(h0)), l1 = f2bf(xv.y - bf2f(h1));
  unsigned short l2 = f2bf(xv.z - bf2f(h2)), l3 = f2bf(xv.w - bf2f(h3));
  unsigned short* dr = dst + (size_t)r * (K * 2) + c;
  uint2 hp, lp;
  hp.x = (unsigned)h0 | ((unsigned)h1 << 16);
  hp.y = (unsigned)h2 | ((unsigned)h3 << 16);
  lp.x = (unsigned)l0 | ((unsigned)l1 << 16);
  lp.y = (unsigned)l2 | ((unsigned)l3 << 16);
  *(uint2*)dr = hp;
  *(uint2*)(dr + K) = lp;
}

// ======================= bf16-split MFMA NT GEMM ===========================
// C[M,N] = A[M,K] * B[N,K]^T with split: K' = 3K, A'=[Ah|Al], B'=[Bh|Bl].
// 128x128 tile, BK=64, 4 waves (2x2), 16x16x32 bf16 MFMA, acc 4x4 frags.
// LDS tiles [128][64] bf16, XOR-swizzled (16B-block idx ^ (row&7)):
// staged via global_load_lds with pre-swizzled per-lane SOURCE addresses,
// read with the same XOR on the ds_read address (conflict-free).
// mode 0: C[m*N+n] = acc + bias[n]        (final linear)
// mode 1: C[(bidx*512+m)*64+hw], n=bidx*64+hw, fp32  (pointwise conv)
__global__ __launch_bounds__(256) void gemm_split_kernel(
    const unsigned short* __restrict__ A, const unsigned short* __restrict__ B,
    float* __restrict__ C, const float* __restrict__ bias,
    int M, int N, int K, int mode)
{
  __shared__ unsigned short sA[8192];   // [128][64]
  __shared__ unsigned short sB[8192];
  const int t = threadIdx.x;
  const int m0 = blockIdx.y * 128, n0 = blockIdx.x * 128;
  const int Kp = 3 * K, twoK = 2 * K, Km = K - 1;
  const int lane = t & 63;
  const int wv = t >> 6;
  const int wm = wv >> 1, wn = wv & 1;
  const int h = lane & 15, g = lane >> 4;

  f32x4 acc[4][4];
#pragma unroll
  for (int mf = 0; mf < 4; ++mf)
#pragma unroll
    for (int nf = 0; nf < 4; ++nf)
      acc[mf][nf] = (f32x4){0.f, 0.f, 0.f, 0.f};

  // staging constants: slot s = it*256+t ; row = s>>3 ; blk = (s&7)^(row&7)
  int srow[4], sblk[4];
#pragma unroll
  for (int it = 0; it < 4; ++it) {
    int s = it * 256 + t;
    srow[it] = s >> 3;
    sblk[it] = (s & 7) ^ (srow[it] & 7);
  }
  const int ldsw = (t & 192) << 4;   // wave-uniform lds base component

  for (int k0 = 0; k0 < Kp; k0 += 64) {
    __syncthreads();
#pragma unroll
    for (int it = 0; it < 4; ++it) {
      int kp = k0 + sblk[it] * 8;
      int ac = (kp < twoK) ? (kp & Km) : (kp - K);
      int bc = (kp < twoK) ? kp : (kp - twoK);
      const unsigned short* ga = A + (size_t)(m0 + srow[it]) * twoK + ac;
      const unsigned short* gb = B + (size_t)(n0 + srow[it]) * twoK + bc;
      __builtin_amdgcn_global_load_lds((gas_t)(const void*)ga,
          (las_t)(void*)((char*)sA + (it * 4096 + ldsw)), 16, 0, 0);
      __builtin_amdgcn_global_load_lds((gas_t)(const void*)gb,
          (las_t)(void*)((char*)sB + (it * 4096 + ldsw)), 16, 0, 0);
    }
    __syncthreads();   // drains vmcnt before barrier -> tiles ready

#pragma unroll
    for (int kk = 0; kk < 2; ++kk) {
      s16x8 af[4], bfr[4];
#pragma unroll
      for (int mf = 0; mf < 4; ++mf) {
        int arow = wm * 64 + mf * 16 + h;
        int aoff = arow * 128 + (((kk * 4 + g) ^ (h & 7)) << 4);
        af[mf] = *(const s16x8*)((const char*)sA + aoff);
      }
#pragma unroll
      for (int nf = 0; nf < 4; ++nf) {
        int brow = wn * 64 + nf * 16 + h;
        int boff = brow * 128 + (((kk * 4 + g) ^ (h & 7)) << 4);
        bfr[nf] = *(const s16x8*)((const char*)sB + boff);
      }
#pragma unroll
      for (int mf = 0; mf < 4; ++mf)
#pragma unroll
        for (int nf = 0; nf < 4; ++nf)
          acc[mf][nf] = __builtin_amdgcn_mfma_f32_16x16x32_bf16(
              af[mf], bfr[nf], acc[mf][nf], 0, 0, 0);
    }
  }

  if (mode == 0) {
#pragma unroll
    for (int mf = 0; mf < 4; ++mf) {
      int mbase = m0 + wm * 64 + mf * 16 + g * 4;
#pragma unroll
      for (int nf = 0; nf < 4; ++nf) {
        int n = n0 + wn * 64 + nf * 16 + h;
        float bv = bias ? bias[n] : 0.f;
#pragma unroll
        for (int qq = 0; qq < 4; ++qq)
          C[(size_t)(mbase + qq) * N + n] = acc[mf][nf][qq] + bv;
      }
    }
  } else {
#pragma unroll
    for (int mf = 0; mf < 4; ++mf) {
      int mbase = m0 + wm * 64 + mf * 16 + g * 4;
#pragma unroll
      for (int nf = 0; nf < 4; ++nf) {
        int n = n0 + wn * 64 + nf * 16 + h;
        int bidx = n >> 6, hw = n & 63;
#pragma unroll
        for (int qq = 0; qq < 4; ++qq)
          C[((size_t)bidx * 512 + mbase + qq) * 64 + hw] = acc[mf][nf][qq];
      }
    }
  }
}

// ======================= Attention (fp32, unchanged) =======================
__global__ __launch_bounds__(256) void attn_kernel(
    const float* __restrict__ u,     // [3][64][512][64]
    const float* __restrict__ pos,   // [2][256][256]
    float* __restrict__ xatt)        // [64][2][256][64]
{
  __shared__ float qs[32][68];
  __shared__ float ks[64][68];
  __shared__ float sc[32][260];
  const int t = threadIdx.x;
  const int rt = blockIdx.x;
  const int cc = blockIdx.y;
  const int b  = blockIdx.z;
  const int i0 = rt * 32;

  const float* Q  = u + ((size_t)(0 * 64 + b) * 512 + cc * 256) * 64;
  const float* Km = u + ((size_t)(1 * 64 + b) * 512 + cc * 256) * 64;
  const float* Vm = u + ((size_t)(2 * 64 + b) * 512 + cc * 256) * 64;

#pragma unroll
  for (int rep = 0; rep < 2; ++rep) {
    int flat = t + rep * 256;
    int r = flat >> 4;
    int kq = (flat & 15) * 4;
    *(float4*)&qs[r][kq] = *(const float4*)(Q + (size_t)(i0 + r) * 64 + kq);
  }

  const int rg = t >> 4;
  const int cg = t & 15;
  const int rg2 = rg * 2;

  for (int chunk = 0; chunk < 4; ++chunk) {
    __syncthreads();
#pragma unroll
    for (int rep = 0; rep < 4; ++rep) {
      int flat = t + rep * 256;
      int jr = flat >> 4; int kq = (flat & 15) * 4;
      *(float4*)&ks[jr][kq] = *(const float4*)(Km + (size_t)(chunk * 64 + jr) * 64 + kq);
    }
    __syncthreads();

    float d2[2][4];
#pragma unroll
    for (int rr = 0; rr < 2; ++rr)
#pragma unroll
      for (int jj = 0; jj < 4; ++jj) d2[rr][jj] = 0.f;

    for (int k4 = 0; k4 < 64; k4 += 4) {
      float4 a0 = *(const float4*)&qs[rg2][k4];
      float4 a1 = *(const float4*)&qs[rg2 + 1][k4];
#pragma unroll
      for (int jj = 0; jj < 4; ++jj) {
        float4 bv = *(const float4*)&ks[cg + 16 * jj][k4];
        d2[0][jj] = fmaf(a0.x, bv.x, fmaf(a0.y, bv.y, fmaf(a0.z, bv.z, fmaf(a0.w, bv.w, d2[0][jj]))));
        d2[1][jj] = fmaf(a1.x, bv.x, fmaf(a1.y, bv.y, fmaf(a1.z, bv.z, fmaf(a1.w, bv.w, d2[1][jj]))));
      }
    }
#pragma unroll
    for (int rr = 0; rr < 2; ++rr)
#pragma unroll
      for (int jj = 0; jj < 4; ++jj) {
        int j = chunk * 64 + cg + 16 * jj;
        int ig = i0 + rg2 + rr;
        sc[rg2 + rr][j] = d2[rr][jj] * 0.125f + pos[((size_t)cc * 256 + ig) * 256 + j];
      }
  }
  __syncthreads();

  {
    const int r = t >> 3;
    const int j8 = t & 7;
    float mx = -3.4e38f;
#pragma unroll
    for (int jj = 0; jj < 32; ++jj) mx = fmaxf(mx, sc[r][j8 + 8 * jj]);
#pragma unroll
    for (int mset = 1; mset < 8; mset <<= 1) mx = fmaxf(mx, __shfl_xor(mx, mset, 64));
    float sum = 0.f;
#pragma unroll
    for (int jj = 0; jj < 32; ++jj) {
      float e = expf(sc[r][j8 + 8 * jj] - mx);
      sc[r][j8 + 8 * jj] = e;
      sum += e;
    }
#pragma unroll
    for (int mset = 1; mset < 8; mset <<= 1) sum += __shfl_xor(sum, mset, 64);
    float inv = 1.f / sum;
#pragma unroll
    for (int jj = 0; jj < 32; ++jj) sc[r][j8 + 8 * jj] *= inv;
  }

  float oacc[2][4];
#pragma unroll
  for (int rr = 0; rr < 2; ++rr)
#pragma unroll
    for (int kk = 0; kk < 4; ++kk) oacc[rr][kk] = 0.f;

  for (int chunk = 0; chunk < 4; ++chunk) {
    __syncthreads();
#pragma unroll
    for (int rep = 0; rep < 4; ++rep) {
      int flat = t + rep * 256;
      int jr = flat >> 4; int kq = (flat & 15) * 4;
      *(float4*)&ks[jr][kq] = *(const float4*)(Vm + (size_t)(chunk * 64 + jr) * 64 + kq);
    }
    __syncthreads();
    for (int jl = 0; jl < 64; ++jl) {
      float p0 = sc[rg2][chunk * 64 + jl];
      float p1 = sc[rg2 + 1][chunk * 64 + jl];
#pragma unroll
      for (int kk = 0; kk < 4; ++kk) {
        float vv = ks[jl][cg + 16 * kk];
        oacc[0][kk] = fmaf(p0, vv, oacc[0][kk]);
        oacc[1][kk] = fmaf(p1, vv, oacc[1][kk]);
      }
    }
  }
#pragma unroll
  for (int rr = 0; rr < 2; ++rr) {
    float* O = xatt + ((size_t)(b * 2 + cc) * 256 + i0 + rg2 + rr) * 64;
#pragma unroll
    for (int kk = 0; kk < 4; ++kk) O[cg + 16 * kk] = oacc[rr][kk];
  }
}

// ======================= rearrange + conv1d -> y1' bf16 hi|lo ==============
__global__ __launch_bounds__(256) void conv1d_kernel(
    const float* __restrict__ xatt, const float* __restrict__ w,
    const float* __restrict__ bias, unsigned short* __restrict__ y1p)
{
  int idx = blockIdx.x * 256 + threadIdx.x;  // 64*32*2048 = 4,194,304
  int l = idx & 2047;
  int o = (idx >> 11) & 31;
  int b = idx >> 16;
  int dd = l >> 3, p2 = l & 7;
  float s = bias[o];
#pragma unroll
  for (int ch = 0; ch < 16; ++ch) {
    int ccc = ch >> 3, p1 = ch & 7;
    float xv = xatt[(((size_t)b * 2 + ccc) * 256 + dd) * 64 + p1 * 8 + p2];
    s = fmaf(xv, w[o * 16 + ch], s);
  }
  unsigned short hi = f2bf(s);
  unsigned short lo = f2bf(s - bf2f(hi));
  size_t rowb = (size_t)(b * 32 + o) * 4096;
  y1p[rowb + l] = hi;
  y1p[rowb + 2048 + l] = lo;
}

// ======================= launch ============================================
extern "C" void kernel_launch(void* const* d_in, const int* in_sizes, int n_in,
                              void* d_out, int out_size, void* d_ws, size_t ws_size,
                              hipStream_t stream) {
  const float* q    = (const float*)d_in[0];
  const float* k    = (const float*)d_in[1];
  const float* v    = (const float*)d_in[2];
  const float* dwk  = (const float*)d_in[3];
  const float* bng  = (const float*)d_in[4];
  const float* bnb  = (const float*)d_in[5];
  const float* bnm  = (const float*)d_in[6];
  const float* bnv  = (const float*)d_in[7];
  const float* pwk  = (const float*)d_in[8];
  const float* pos  = (const float*)d_in[9];
  const float* c1w  = (const float*)d_in[10];
  const float* c1b  = (const float*)d_in[11];
  const float* linw = (const float*)d_in[12];
  const float* linb = (const float*)d_in[13];
  float* out = (float*)d_out;

  if (ws_size < 50331648u) return;

  char* ws = (char*)d_ws;
  float*          u    = (float*)(ws + 0);                   // 25,165,824 B
  unsigned short* tTp  = (unsigned short*)(ws + 25165824);   // 12,582,912 B
  unsigned short* pwkp = (unsigned short*)(ws + 37748736);   //  1,048,576 B
  float*          xatt = (float*)(ws + 25165824);            //  8,388,608 B
  unsigned short* y1p  = (unsigned short*)(ws + 0);          // 16,777,216 B
  unsigned short* lwp  = (unsigned short*)(ws + 16777216);   // 33,554,432 B

  for (int i = 0; i < 3; ++i) {
    const float* x = (i == 0) ? q : (i == 1) ? k : v;
    stageA_kernel<<<8192, 256, 0, stream>>>(
        x, dwk + (size_t)i * 512 * 9, bng + i * 512, bnb + i * 512,
        bnm + i * 512, bnv + i * 512, tTp);
    split_kernel<<<256, 256, 0, stream>>>(pwk + (size_t)i * 512 * 512, pwkp, 9, 65536);
    dim3 g1(32, 4);
    gemm_split_kernel<<<g1, 256, 0, stream>>>(
        pwkp, tTp, u + (size_t)i * 2097152, nullptr, 512, 4096, 512, 1);
  }

  dim3 g2(8, 2, 64);
  attn_kernel<<<g2, 256, 0, stream>>>(u, pos, xatt);

  conv1d_kernel<<<16384, 256, 0, stream>>>(xatt, c1w, c1b, y1p);

  split_kernel<<<8192, 256, 0, stream>>>(linw, lwp, 11, 2097152);

  dim3 g3(32, 16);
  gemm_split_kernel<<<g3, 256, 0, stream>>>(y1p, lwp, out, linb, 2048, 4096, 2048, 0);
}

// Round 3
// 326.781 us; speedup vs baseline: 2.3271x; 1.4190x over previous
//
#include <hip/hip_runtime.h>

// ---------------------------------------------------------------------------
// Geometry: b=64, units=32, d_model=4096, P=16 -> c=2, d=256, C=512,
// dwconv 3x3 s2 16x16->8x8 (hw=64), dk=64; attn 256x256 per (b,cc);
// conv1d 16->32 over l=2048; linear 2048->4096.
//
// GEMMs run as bf16 hi/lo split MFMA:  C = Ah*Bh + Ah*Bl + Al*Bh  (K' = 3K),
// A' stored [Ah|Al] ([M][2K] bf16), B' stored [Bh|Bl] ([N][2K] bf16);
// K'-segment -> stored-column remap happens in the staging addresses.
//
// Workspace (bytes), ws >= 50331648:
//   phase1 (x3 loop): u fp32 [3][64][512][64] @ 0            (25,165,824)
//                     tT'_i bf16 [4096][1024] @ 25,165,824   (12,582,912)
//                     pwk'_i bf16 [512][1024] @ 37,748,736   ( 1,048,576)
//   phase2: xatt fp32 [64][2][256][64]        @ 25,165,824   ( 8,388,608)
//   phase3: y1' bf16 [2048][4096]             @ 0            (16,777,216)
//           linw' bf16 [4096][4096]           @ 16,777,216   (33,554,432)
// ---------------------------------------------------------------------------

typedef short s16x8 __attribute__((ext_vector_type(8)));
typedef float f32x4 __attribute__((ext_vector_type(4)));
typedef const __attribute__((address_space(1))) void* gas_t;
typedef __attribute__((address_space(3))) void* las_t;

__device__ __forceinline__ unsigned short f2bf(float x) {
  unsigned u = __float_as_uint(x);
  unsigned r = u + 0x7fffu + ((u >> 16) & 1u);
  return (unsigned short)(r >> 16);
}
__device__ __forceinline__ float bf2f(unsigned short h) {
  return __uint_as_float((unsigned)h << 16);
}

// ======================= Stage A: patch + dwconv + BN + GELU ===============
// Block = (b, cc, oh); thread = dd. Coalesced float4 row loads, 8 ow/thread.
// Writes tT'_i bf16 [4096 rows=(b*64+hw)][1024 = hi|lo].
__global__ __launch_bounds__(256) void stageA_kernel(
    const float* __restrict__ x, const float* __restrict__ dwk_i,
    const float* __restrict__ bng, const float* __restrict__ bnb,
    const float* __restrict__ bnm, const float* __restrict__ bnv,
    unsigned short* __restrict__ tTp)
{
  const int dd = threadIdx.x;              // 0..255
  const int oh = blockIdx.x & 7;
  const int cc = (blockIdx.x >> 3) & 1;
  const int b  = blockIdx.x >> 4;
  const int ch = cc * 256 + dd;

  float r[3][16];
#pragma unroll
  for (int kh = 0; kh < 3; ++kh) {
    int ih = 2 * oh - 1 + kh;
    if (ih >= 0 && ih <= 15) {
      const float* p = x + (size_t)(b * 32 + cc * 16 + ih) * 4096 + dd * 16;
#pragma unroll
      for (int jq = 0; jq < 4; ++jq)
        *(float4*)&r[kh][jq * 4] = *(const float4*)(p + jq * 4);
    } else {
#pragma unroll
      for (int j = 0; j < 16; ++j) r[kh][j] = 0.f;
    }
  }
  float w9[9];
#pragma unroll
  for (int j = 0; j < 9; ++j) w9[j] = dwk_i[ch * 9 + j];
  const float scale = bng[ch] / sqrtf(bnv[ch] + 1e-5f);
  const float shift = bnb[ch] - bnm[ch] * scale;

#pragma unroll
  for (int ow = 0; ow < 8; ++ow) {
    float acc = 0.f;
#pragma unroll
    for (int kh = 0; kh < 3; ++kh)
#pragma unroll
      for (int kw = 0; kw < 3; ++kw) {
        int iw = 2 * ow - 1 + kw;
        if (iw >= 0 && iw <= 15) acc = fmaf(r[kh][iw], w9[kh * 3 + kw], acc);
      }
    float y = acc * scale + shift;
    y = 0.5f * y * (1.f + erff(y * 0.70710678118654752f));
    unsigned short hi = f2bf(y);
    unsigned short lo = f2bf(y - bf2f(hi));
    size_t rowb = (size_t)(b * 64 + oh * 8 + ow) * 1024;
    tTp[rowb + ch] = hi;
    tTp[rowb + 512 + ch] = lo;
  }
}

// ======================= fp32 -> bf16 hi|lo split ==========================
__global__ __launch_bounds__(256) void split_kernel(
    const float* __restrict__ src, unsigned short* __restrict__ dst,
    int kshift, int total4)
{
  int i = blockIdx.x * 256 + threadIdx.x;
  if (i >= total4) return;
  size_t i4 = (size_t)i * 4;
  int K = 1 << kshift;
  int r = (int)(i4 >> kshift);
  int c = (int)(i4 & (size_t)(K - 1));
  float4 xv = *(const float4*)(src + i4);
  unsigned short h0 = f2bf(xv.x), h1 = f2bf(xv.y), h2 = f2bf(xv.z), h3 = f2bf(xv.w);
  unsigned short l0 = f2bf(xv.x - bf2f(h0)), l1 = f2bf(xv.y - bf2f(h1));
  unsigned short l2 = f2bf(xv.z - bf2f(h2)), l3 = f2bf(xv.w - bf2f(h3));
  unsigned short* dr = dst + (size_t)r * (K * 2) + c;
  uint2 hp, lp;
  hp.x = (unsigned)h0 | ((unsigned)h1 << 16);
  hp.y = (unsigned)h2 | ((unsigned)h3 << 16);
  lp.x = (unsigned)l0 | ((unsigned)l1 << 16);
  lp.y = (unsigned)l2 | ((unsigned)l3 << 16);
  *(uint2*)dr = hp;
  *(uint2*)(dr + K) = lp;
}

// ======================= bf16-split MFMA NT GEMM ===========================
// C[M,N] = A[M,K]*B[N,K]^T, split K'=3K. Tile BM x 128, 4 waves, BK=64,
// 16x16x32 bf16 MFMA. BM=128: waves 2x2, 4x4 frags. BM=64: waves 1x4, 4x2.
// LDS [BM|128][64] bf16 XOR-swizzled (16B-blk ^ row&7) via pre-swizzled
// global_load_lds source addresses; same XOR on ds_read -> conflict-free.
// mode 0: C[m*N+n] += bias[n]  (final linear)
// mode 1: C[(bidx*512+m)*64+hw], n=bidx*64+hw  (pointwise conv, fp32)
template<int BM>
__global__ __launch_bounds__(256) void gemm_split_kernel(
    const unsigned short* __restrict__ A, const unsigned short* __restrict__ B,
    float* __restrict__ C, const float* __restrict__ bias,
    int M, int N, int K, int mode)
{
  constexpr int AITERS = BM / 32;                 // 4 or 2
  constexpr int NF = (BM == 128) ? 4 : 2;
  __shared__ unsigned short sA[BM * 64];
  __shared__ unsigned short sB[8192];
  const int t = threadIdx.x;
  const int m0 = blockIdx.y * BM, n0 = blockIdx.x * 128;
  const int Kp = 3 * K, twoK = 2 * K, Km = K - 1;
  const int lane = t & 63;
  const int wv = t >> 6;
  const int wm = (BM == 128) ? (wv >> 1) : 0;
  const int colbase = (BM == 128) ? ((wv & 1) * 64) : (wv * 32);
  const int h = lane & 15, g = lane >> 4;

  f32x4 acc[4][NF];
#pragma unroll
  for (int mf = 0; mf < 4; ++mf)
#pragma unroll
    for (int nf = 0; nf < NF; ++nf)
      acc[mf][nf] = (f32x4){0.f, 0.f, 0.f, 0.f};

  int srow[4], sblk[4];
#pragma unroll
  for (int it = 0; it < 4; ++it) {
    int s = it * 256 + t;
    srow[it] = s >> 3;
    sblk[it] = (s & 7) ^ (srow[it] & 7);
  }
  const int ldsw = (t & 192) << 4;

  for (int k0 = 0; k0 < Kp; k0 += 64) {
    __syncthreads();
#pragma unroll
    for (int it = 0; it < AITERS; ++it) {
      int kp = k0 + sblk[it] * 8;
      int ac = (kp < twoK) ? (kp & Km) : (kp - K);
      const unsigned short* ga = A + (size_t)(m0 + srow[it]) * twoK + ac;
      __builtin_amdgcn_global_load_lds((gas_t)(const void*)ga,
          (las_t)(void*)((char*)sA + (it * 4096 + ldsw)), 16, 0, 0);
    }
#pragma unroll
    for (int it = 0; it < 4; ++it) {
      int kp = k0 + sblk[it] * 8;
      int bc = (kp < twoK) ? kp : (kp - twoK);
      const unsigned short* gb = B + (size_t)(n0 + srow[it]) * twoK + bc;
      __builtin_amdgcn_global_load_lds((gas_t)(const void*)gb,
          (las_t)(void*)((char*)sB + (it * 4096 + ldsw)), 16, 0, 0);
    }
    __syncthreads();

#pragma unroll
    for (int kk = 0; kk < 2; ++kk) {
      s16x8 af[4], bfr[NF];
#pragma unroll
      for (int mf = 0; mf < 4; ++mf) {
        int arow = wm * 64 + mf * 16 + h;
        int aoff = arow * 128 + (((kk * 4 + g) ^ (h & 7)) << 4);
        af[mf] = *(const s16x8*)((const char*)sA + aoff);
      }
#pragma unroll
      for (int nf = 0; nf < NF; ++nf) {
        int brow = colbase + nf * 16 + h;
        int boff = brow * 128 + (((kk * 4 + g) ^ (h & 7)) << 4);
        bfr[nf] = *(const s16x8*)((const char*)sB + boff);
      }
#pragma unroll
      for (int mf = 0; mf < 4; ++mf)
#pragma unroll
        for (int nf = 0; nf < NF; ++nf)
          acc[mf][nf] = __builtin_amdgcn_mfma_f32_16x16x32_bf16(
              af[mf], bfr[nf], acc[mf][nf], 0, 0, 0);
    }
  }

  if (mode == 0) {
#pragma unroll
    for (int mf = 0; mf < 4; ++mf) {
      int mbase = m0 + wm * 64 + mf * 16 + g * 4;
#pragma unroll
      for (int nf = 0; nf < NF; ++nf) {
        int n = n0 + colbase + nf * 16 + h;
        float bv = bias ? bias[n] : 0.f;
#pragma unroll
        for (int qq = 0; qq < 4; ++qq)
          C[(size_t)(mbase + qq) * N + n] = acc[mf][nf][qq] + bv;
      }
    }
  } else {
#pragma unroll
    for (int mf = 0; mf < 4; ++mf) {
      int mbase = m0 + wm * 64 + mf * 16 + g * 4;
#pragma unroll
      for (int nf = 0; nf < NF; ++nf) {
        int n = n0 + colbase + nf * 16 + h;
        int bidx = n >> 6, hw = n & 63;
#pragma unroll
        for (int qq = 0; qq < 4; ++qq)
          C[((size_t)bidx * 512 + mbase + qq) * 64 + hw] = acc[mf][nf][qq];
      }
    }
  }
}

// ======================= Attention (fp32) ==================================
__global__ __launch_bounds__(256) void attn_kernel(
    const float* __restrict__ u,     // [3][64][512][64]
    const float* __restrict__ pos,   // [2][256][256]
    float* __restrict__ xatt)        // [64][2][256][64]
{
  __shared__ float qs[32][68];
  __shared__ float ks[64][68];
  __shared__ float sc[32][260];
  const int t = threadIdx.x;
  const int rt = blockIdx.x;
  const int cc = blockIdx.y;
  const int b  = blockIdx.z;
  const int i0 = rt * 32;

  const float* Q  = u + ((size_t)(0 * 64 + b) * 512 + cc * 256) * 64;
  const float* Km = u + ((size_t)(1 * 64 + b) * 512 + cc * 256) * 64;
  const float* Vm = u + ((size_t)(2 * 64 + b) * 512 + cc * 256) * 64;

#pragma unroll
  for (int rep = 0; rep < 2; ++rep) {
    int flat = t + rep * 256;
    int r = flat >> 4;
    int kq = (flat & 15) * 4;
    *(float4*)&qs[r][kq] = *(const float4*)(Q + (size_t)(i0 + r) * 64 + kq);
  }

  const int rg = t >> 4;
  const int cg = t & 15;
  const int rg2 = rg * 2;

  // -------- scores --------
  for (int chunk = 0; chunk < 4; ++chunk) {
    __syncthreads();
#pragma unroll
    for (int rep = 0; rep < 4; ++rep) {
      int flat = t + rep * 256;
      int jr = flat >> 4; int kq = (flat & 15) * 4;
      *(float4*)&ks[jr][kq] = *(const float4*)(Km + (size_t)(chunk * 64 + jr) * 64 + kq);
    }
    __syncthreads();

    float d2[2][4];
#pragma unroll
    for (int rr = 0; rr < 2; ++rr)
#pragma unroll
      for (int jj = 0; jj < 4; ++jj) d2[rr][jj] = 0.f;

    for (int k4 = 0; k4 < 64; k4 += 4) {
      float4 a0 = *(const float4*)&qs[rg2][k4];
      float4 a1 = *(const float4*)&qs[rg2 + 1][k4];
#pragma unroll
      for (int jj = 0; jj < 4; ++jj) {
        float4 bv = *(const float4*)&ks[cg + 16 * jj][k4];
        d2[0][jj] = fmaf(a0.x, bv.x, fmaf(a0.y, bv.y, fmaf(a0.z, bv.z, fmaf(a0.w, bv.w, d2[0][jj]))));
        d2[1][jj] = fmaf(a1.x, bv.x, fmaf(a1.y, bv.y, fmaf(a1.z, bv.z, fmaf(a1.w, bv.w, d2[1][jj]))));
      }
    }
#pragma unroll
    for (int rr = 0; rr < 2; ++rr)
#pragma unroll
      for (int jj = 0; jj < 4; ++jj) {
        int j = chunk * 64 + cg + 16 * jj;
        int ig = i0 + rg2 + rr;
        sc[rg2 + rr][j] = d2[rr][jj] * 0.125f + pos[((size_t)cc * 256 + ig) * 256 + j];
      }
  }
  __syncthreads();

  // -------- softmax --------
  {
    const int r = t >> 3;
    const int j8 = t & 7;
    float mx = -3.4e38f;
#pragma unroll
    for (int jj = 0; jj < 32; ++jj) mx = fmaxf(mx, sc[r][j8 + 8 * jj]);
#pragma unroll
    for (int mset = 1; mset < 8; mset <<= 1) mx = fmaxf(mx, __shfl_xor(mx, mset, 64));
    float sum = 0.f;
#pragma unroll
    for (int jj = 0; jj < 32; ++jj) {
      float e = expf(sc[r][j8 + 8 * jj] - mx);
      sc[r][j8 + 8 * jj] = e;
      sum += e;
    }
#pragma unroll
    for (int mset = 1; mset < 8; mset <<= 1) sum += __shfl_xor(sum, mset, 64);
    float inv = 1.f / sum;
#pragma unroll
    for (int jj = 0; jj < 32; ++jj) sc[r][j8 + 8 * jj] *= inv;
  }

  // -------- PV (thread's 4 cols contiguous -> float4 LDS ops) --------
  f32x4 oacc[2];
  oacc[0] = (f32x4){0.f, 0.f, 0.f, 0.f};
  oacc[1] = (f32x4){0.f, 0.f, 0.f, 0.f};

  for (int chunk = 0; chunk < 4; ++chunk) {
    __syncthreads();
#pragma unroll
    for (int rep = 0; rep < 4; ++rep) {
      int flat = t + rep * 256;
      int jr = flat >> 4; int kq = (flat & 15) * 4;
      *(float4*)&ks[jr][kq] = *(const float4*)(Vm + (size_t)(chunk * 64 + jr) * 64 + kq);
    }
    __syncthreads();
    for (int jl = 0; jl < 64; ++jl) {
      float p0 = sc[rg2][chunk * 64 + jl];
      float p1 = sc[rg2 + 1][chunk * 64 + jl];
      f32x4 vv = *(const f32x4*)&ks[jl][cg * 4];
#pragma unroll
      for (int kk = 0; kk < 4; ++kk) {
        oacc[0][kk] = fmaf(p0, vv[kk], oacc[0][kk]);
        oacc[1][kk] = fmaf(p1, vv[kk], oacc[1][kk]);
      }
    }
  }
#pragma unroll
  for (int rr = 0; rr < 2; ++rr) {
    float* O = xatt + ((size_t)(b * 2 + cc) * 256 + i0 + rg2 + rr) * 64;
    *(f32x4*)&O[cg * 4] = oacc[rr];
  }
}

// ======================= rearrange + conv1d -> y1' bf16 hi|lo ==============
// Block = (lt, b); 512 threads, one l each; X tile staged in LDS once.
__global__ __launch_bounds__(512) void conv1d_kernel(
    const float* __restrict__ xatt, const float* __restrict__ w,
    const float* __restrict__ bias, unsigned short* __restrict__ y1p)
{
  __shared__ float X[16][520];
  __shared__ float W[512];
  __shared__ float Bp[32];
  const int t = threadIdx.x;       // 0..511
  const int lt = blockIdx.x;       // 0..3
  const int b  = blockIdx.y;       // 0..63
  if (t < 512) W[t] = w[t];
  if (t < 32) Bp[t] = bias[t];
#pragma unroll
  for (int cc = 0; cc < 2; ++cc) {
    const float* src = xatt + ((size_t)(b * 2 + cc) * 256 + lt * 64) * 64;
#pragma unroll
    for (int pass = 0; pass < 2; ++pass) {
      int f4 = t + pass * 512;               // 0..1023 float4 units
      float4 v4 = *(const float4*)(src + (size_t)f4 * 4);
      int fl = f4 * 4;
      int dl = fl >> 6;
      int rr = fl & 63;
      int p1 = rr >> 3, p2 = rr & 7;
      *(float4*)&X[cc * 8 + p1][dl * 8 + p2] = v4;
    }
  }
  __syncthreads();

  float xv[16];
#pragma unroll
  for (int ch = 0; ch < 16; ++ch) xv[ch] = X[ch][t];

  size_t obase = (size_t)b * 32 * 4096 + lt * 512 + t;
#pragma unroll
  for (int o = 0; o < 32; ++o) {
    float s = Bp[o];
#pragma unroll
    for (int ch = 0; ch < 16; ++ch) s = fmaf(xv[ch], W[o * 16 + ch], s);
    unsigned short hi = f2bf(s);
    unsigned short lo = f2bf(s - bf2f(hi));
    y1p[obase + (size_t)o * 4096] = hi;
    y1p[obase + (size_t)o * 4096 + 2048] = lo;
  }
}

// ======================= launch ============================================
extern "C" void kernel_launch(void* const* d_in, const int* in_sizes, int n_in,
                              void* d_out, int out_size, void* d_ws, size_t ws_size,
                              hipStream_t stream) {
  const float* q    = (const float*)d_in[0];
  const float* k    = (const float*)d_in[1];
  const float* v    = (const float*)d_in[2];
  const float* dwk  = (const float*)d_in[3];
  const float* bng  = (const float*)d_in[4];
  const float* bnb  = (const float*)d_in[5];
  const float* bnm  = (const float*)d_in[6];
  const float* bnv  = (const float*)d_in[7];
  const float* pwk  = (const float*)d_in[8];
  const float* pos  = (const float*)d_in[9];
  const float* c1w  = (const float*)d_in[10];
  const float* c1b  = (const float*)d_in[11];
  const float* linw = (const float*)d_in[12];
  const float* linb = (const float*)d_in[13];
  float* out = (float*)d_out;

  if (ws_size < 50331648u) return;

  char* ws = (char*)d_ws;
  float*          u    = (float*)(ws + 0);                   // 25,165,824 B
  unsigned short* tTp  = (unsigned short*)(ws + 25165824);   // 12,582,912 B
  unsigned short* pwkp = (unsigned short*)(ws + 37748736);   //  1,048,576 B
  float*          xatt = (float*)(ws + 25165824);            //  8,388,608 B
  unsigned short* y1p  = (unsigned short*)(ws + 0);          // 16,777,216 B
  unsigned short* lwp  = (unsigned short*)(ws + 16777216);   // 33,554,432 B

  for (int i = 0; i < 3; ++i) {
    const float* x = (i == 0) ? q : (i == 1) ? k : v;
    stageA_kernel<<<1024, 256, 0, stream>>>(
        x, dwk + (size_t)i * 512 * 9, bng + i * 512, bnb + i * 512,
        bnm + i * 512, bnv + i * 512, tTp);
    split_kernel<<<256, 256, 0, stream>>>(pwk + (size_t)i * 512 * 512, pwkp, 9, 65536);
    dim3 g1(32, 8);
    gemm_split_kernel<64><<<g1, 256, 0, stream>>>(
        pwkp, tTp, u + (size_t)i * 2097152, nullptr, 512, 4096, 512, 1);
  }

  dim3 g2(8, 2, 64);
  attn_kernel<<<g2, 256, 0, stream>>>(u, pos, xatt);

  conv1d_kernel<<<dim3(4, 64), 512, 0, stream>>>(xatt, c1w, c1b, y1p);

  split_kernel<<<8192, 256, 0, stream>>>(linw, lwp, 11, 2097152);

  dim3 g3(32, 16);
  gemm_split_kernel<128><<<g3, 256, 0, stream>>>(y1p, lwp, out, linb, 2048, 4096, 2048, 0);
}

// Round 4
// 300.207 us; speedup vs baseline: 2.5330x; 1.0885x over previous
//
#include <hip/hip_runtime.h>

// ---------------------------------------------------------------------------
// Geometry: b=64, units=32, d_model=4096, P=16 -> c=2, d=256, C=512,
// dwconv 3x3 s2 16x16->8x8 (hw=64), dk=64; attn 256x256 per (b,cc);
// conv1d 16->32 over l=2048; linear 2048->4096.
//
// GEMMs run as bf16 hi/lo split MFMA:  C = Ah*Bh + Ah*Bl + Al*Bh  (K' = 3K),
// A' stored [Ah|Al] ([M][2K] bf16), B' stored [Bh|Bl] ([N][2K] bf16);
// K'-segment -> stored-column remap happens in the staging addresses.
//
// Final linear uses gemm_pipe_kernel: BM=256 BN=128 BK=64, 8 waves, 3 LDS
// buffers (144 KB), 4 phases/K-tile, counted s_waitcnt vmcnt(6) (T3+T4),
// setprio around MFMA clusters (T5), XOR-swizzled LDS (T2), XCD swizzle (T1).
//
// Workspace (bytes), ws >= 50331648:
//   phase1 (x3 loop): u fp32 [3][64][512][64] @ 0            (25,165,824)
//                     tT'_i bf16 [4096][1024] @ 25,165,824   (12,582,912)
//                     pwk'_i bf16 [512][1024] @ 37,748,736   ( 1,048,576)
//   phase2: xatt fp32 [64][2][256][64]        @ 25,165,824   ( 8,388,608)
//   phase3: y1' bf16 [2048][4096]             @ 0            (16,777,216)
//           linw' bf16 [4096][4096]           @ 16,777,216   (33,554,432)
// ---------------------------------------------------------------------------

typedef short s16x8 __attribute__((ext_vector_type(8)));
typedef float f32x4 __attribute__((ext_vector_type(4)));
typedef const __attribute__((address_space(1))) void* gas_t;
typedef __attribute__((address_space(3))) void* las_t;

__device__ __forceinline__ unsigned short f2bf(float x) {
  unsigned u = __float_as_uint(x);
  unsigned r = u + 0x7fffu + ((u >> 16) & 1u);
  return (unsigned short)(r >> 16);
}
__device__ __forceinline__ float bf2f(unsigned short h) {
  return __uint_as_float((unsigned)h << 16);
}

// ======================= Stage A: patch + dwconv + BN + GELU ===============
__global__ __launch_bounds__(256) void stageA_kernel(
    const float* __restrict__ x, const float* __restrict__ dwk_i,
    const float* __restrict__ bng, const float* __restrict__ bnb,
    const float* __restrict__ bnm, const float* __restrict__ bnv,
    unsigned short* __restrict__ tTp)
{
  const int dd = threadIdx.x;              // 0..255
  const int oh = blockIdx.x & 7;
  const int cc = (blockIdx.x >> 3) & 1;
  const int b  = blockIdx.x >> 4;
  const int ch = cc * 256 + dd;

  float r[3][16];
#pragma unroll
  for (int kh = 0; kh < 3; ++kh) {
    int ih = 2 * oh - 1 + kh;
    if (ih >= 0 && ih <= 15) {
      const float* p = x + (size_t)(b * 32 + cc * 16 + ih) * 4096 + dd * 16;
#pragma unroll
      for (int jq = 0; jq < 4; ++jq)
        *(float4*)&r[kh][jq * 4] = *(const float4*)(p + jq * 4);
    } else {
#pragma unroll
      for (int j = 0; j < 16; ++j) r[kh][j] = 0.f;
    }
  }
  float w9[9];
#pragma unroll
  for (int j = 0; j < 9; ++j) w9[j] = dwk_i[ch * 9 + j];
  const float scale = bng[ch] / sqrtf(bnv[ch] + 1e-5f);
  const float shift = bnb[ch] - bnm[ch] * scale;

#pragma unroll
  for (int ow = 0; ow < 8; ++ow) {
    float acc = 0.f;
#pragma unroll
    for (int kh = 0; kh < 3; ++kh)
#pragma unroll
      for (int kw = 0; kw < 3; ++kw) {
        int iw = 2 * ow - 1 + kw;
        if (iw >= 0 && iw <= 15) acc = fmaf(r[kh][iw], w9[kh * 3 + kw], acc);
      }
    float y = acc * scale + shift;
    y = 0.5f * y * (1.f + erff(y * 0.70710678118654752f));
    unsigned short hi = f2bf(y);
    unsigned short lo = f2bf(y - bf2f(hi));
    size_t rowb = (size_t)(b * 64 + oh * 8 + ow) * 1024;
    tTp[rowb + ch] = hi;
    tTp[rowb + 512 + ch] = lo;
  }
}

// ======================= fp32 -> bf16 hi|lo split ==========================
__global__ __launch_bounds__(256) void split_kernel(
    const float* __restrict__ src, unsigned short* __restrict__ dst,
    int kshift, int total4)
{
  int i = blockIdx.x * 256 + threadIdx.x;
  if (i >= total4) return;
  size_t i4 = (size_t)i * 4;
  int K = 1 << kshift;
  int r = (int)(i4 >> kshift);
  int c = (int)(i4 & (size_t)(K - 1));
  float4 xv = *(const float4*)(src + i4);
  unsigned short h0 = f2bf(xv.x), h1 = f2bf(xv.y), h2 = f2bf(xv.z), h3 = f2bf(xv.w);
  unsigned short l0 = f2bf(xv.x - bf2f(h0)), l1 = f2bf(xv.y - bf2f(h1));
  unsigned short l2 = f2bf(xv.z - bf2f(h2)), l3 = f2bf(xv.w - bf2f(h3));
  unsigned short* dr = dst + (size_t)r * (K * 2) + c;
  uint2 hp, lp;
  hp.x = (unsigned)h0 | ((unsigned)h1 << 16);
  hp.y = (unsigned)h2 | ((unsigned)h3 << 16);
  lp.x = (unsigned)l0 | ((unsigned)l1 << 16);
  lp.y = (unsigned)l2 | ((unsigned)l3 << 16);
  *(uint2*)dr = hp;
  *(uint2*)(dr + K) = lp;
}

// ======================= pointwise: bf16-split MFMA NT GEMM (2-barrier) ====
// BM=64 x 128 tile, 4 waves 1x4, used for the 512x4096x(3*512) pointwise conv.
__global__ __launch_bounds__(256) void gemm_split_kernel(
    const unsigned short* __restrict__ A, const unsigned short* __restrict__ B,
    float* __restrict__ C, int M, int N, int K)
{
  __shared__ unsigned short sA[4096];    // [64][64]
  __shared__ unsigned short sB[8192];    // [128][64]
  const int t = threadIdx.x;
  const int m0 = blockIdx.y * 64, n0 = blockIdx.x * 128;
  const int Kp = 3 * K, twoK = 2 * K, Km = K - 1;
  const int lane = t & 63;
  const int wv = t >> 6;
  const int colbase = wv * 32;
  const int h = lane & 15, g = lane >> 4;

  f32x4 acc[4][2];
#pragma unroll
  for (int mf = 0; mf < 4; ++mf)
#pragma unroll
    for (int nf = 0; nf < 2; ++nf)
      acc[mf][nf] = (f32x4){0.f, 0.f, 0.f, 0.f};

  int srow[4], sblk[4];
#pragma unroll
  for (int it = 0; it < 4; ++it) {
    int s = it * 256 + t;
    srow[it] = s >> 3;
    sblk[it] = (s & 7) ^ (srow[it] & 7);
  }
  const int ldsw = (t & 192) << 4;

  for (int k0 = 0; k0 < Kp; k0 += 64) {
    __syncthreads();
#pragma unroll
    for (int it = 0; it < 2; ++it) {
      int kp = k0 + sblk[it] * 8;
      int ac = (kp < twoK) ? (kp & Km) : (kp - K);
      const unsigned short* ga = A + (size_t)(m0 + srow[it]) * twoK + ac;
      __builtin_amdgcn_global_load_lds((gas_t)(const void*)ga,
          (las_t)(void*)((char*)sA + (it * 4096 + ldsw)), 16, 0, 0);
    }
#pragma unroll
    for (int it = 0; it < 4; ++it) {
      int kp = k0 + sblk[it] * 8;
      int bc = (kp < twoK) ? kp : (kp - twoK);
      const unsigned short* gb = B + (size_t)(n0 + srow[it]) * twoK + bc;
      __builtin_amdgcn_global_load_lds((gas_t)(const void*)gb,
          (las_t)(void*)((char*)sB + (it * 4096 + ldsw)), 16, 0, 0);
    }
    __syncthreads();

#pragma unroll
    for (int kk = 0; kk < 2; ++kk) {
      s16x8 af[4], bfr[2];
#pragma unroll
      for (int mf = 0; mf < 4; ++mf) {
        int arow = mf * 16 + h;
        int aoff = arow * 128 + (((kk * 4 + g) ^ (h & 7)) << 4);
        af[mf] = *(const s16x8*)((const char*)sA + aoff);
      }
#pragma unroll
      for (int nf = 0; nf < 2; ++nf) {
        int brow = colbase + nf * 16 + h;
        int boff = brow * 128 + (((kk * 4 + g) ^ (h & 7)) << 4);
        bfr[nf] = *(const s16x8*)((const char*)sB + boff);
      }
#pragma unroll
      for (int mf = 0; mf < 4; ++mf)
#pragma unroll
        for (int nf = 0; nf < 2; ++nf)
          acc[mf][nf] = __builtin_amdgcn_mfma_f32_16x16x32_bf16(
              af[mf], bfr[nf], acc[mf][nf], 0, 0, 0);
    }
  }

  // store u[(bidx*512 + m)*64 + hw], n = bidx*64+hw
#pragma unroll
  for (int mf = 0; mf < 4; ++mf) {
    int mbase = m0 + mf * 16 + g * 4;
#pragma unroll
    for (int nf = 0; nf < 2; ++nf) {
      int n = n0 + colbase + nf * 16 + h;
      int bidx = n >> 6, hw = n & 63;
#pragma unroll
      for (int qq = 0; qq < 4; ++qq)
        C[((size_t)bidx * 512 + mbase + qq) * 64 + hw] = acc[mf][nf][qq];
    }
  }
}

// ======================= final linear: deep-pipelined split GEMM ===========
// C[M,N] = A[M,K]*B[N,K]^T + bias, split K'=3K. BM=256, BN=128, BK=64.
// 8 waves (wm=wv&3 row-64-band, wn=wv>>2 col-64-band), 4x4 16x16 frags/wave.
// 3 LDS buffers x (A 32KB + B 16KB) = 144 KB; prefetch 2 tiles ahead;
// vmcnt(6) once per K-tile retires the previous tile's 6 loads (never 0).
// Launched with grid (32, 8) ONLY (hardcoded swizzle shifts).
__global__ __launch_bounds__(512, 2) void gemm_pipe_kernel(
    const unsigned short* __restrict__ A, const unsigned short* __restrict__ B,
    float* __restrict__ C, const float* __restrict__ bias,
    int M, int N, int K)
{
  __shared__ unsigned short lds[73728];    // 147456 B = 3 x 49152
  const int t = threadIdx.x;

  // T1: bijective XCD swizzle; nwg = 256, contiguous chunk of 32 per XCD
  const int flat = blockIdx.y * 32 + blockIdx.x;
  const int swz = (flat & 7) * 32 + (flat >> 3);
  const int n0 = (swz & 31) * 128;
  const int m0 = (swz >> 5) * 256;

  const int twoK = 2 * K, Km = K - 1;
  const int nt = (3 * K) >> 6;             // K-tiles (>= 3)

  const int lane = t & 63;
  const int wv = t >> 6;
  const int wm = wv & 3, wn = wv >> 2;
  const int h = lane & 15, g = lane >> 4;

  f32x4 acc[4][4];
#pragma unroll
  for (int mf = 0; mf < 4; ++mf)
#pragma unroll
    for (int nf = 0; nf < 4; ++nf)
      acc[mf][nf] = (f32x4){0.f, 0.f, 0.f, 0.f};

  // staging constants: A slots s = it*512+t (it<4), B slots (it<2)
  int arow[4], ablk[4], brow[2], bblk[2];
#pragma unroll
  for (int it = 0; it < 4; ++it) {
    int s = it * 512 + t;
    arow[it] = s >> 3;
    ablk[it] = (t & 7) ^ (arow[it] & 7);
  }
#pragma unroll
  for (int it = 0; it < 2; ++it) {
    int s = it * 512 + t;
    brow[it] = s >> 3;
    bblk[it] = (t & 7) ^ (brow[it] & 7);
  }

  auto issueA = [&](int buf, int tt, int it) {
    int kp = tt * 64 + ablk[it] * 8;
    int ac = (kp < twoK) ? (kp & Km) : (kp - K);
    __builtin_amdgcn_global_load_lds(
        (gas_t)(const void*)(A + (size_t)(m0 + arow[it]) * twoK + ac),
        (las_t)(void*)((char*)lds + (buf * 49152 + it * 8192 + t * 16)), 16, 0, 0);
  };
  auto issueB = [&](int buf, int tt, int it) {
    int kp = tt * 64 + bblk[it] * 8;
    int bc = (kp < twoK) ? kp : (kp - twoK);
    __builtin_amdgcn_global_load_lds(
        (gas_t)(const void*)(B + (size_t)(n0 + brow[it]) * twoK + bc),
        (las_t)(void*)((char*)lds + (buf * 49152 + 32768 + it * 8192 + t * 16)), 16, 0, 0);
  };

  const int aoffb = (wm * 64 + h) * 128;
  const int boffb = 32768 + (wn * 64 + h) * 128;
  int colx[2];
  colx[0] = ((g) ^ (h & 7)) << 4;
  colx[1] = ((4 + g) ^ (h & 7)) << 4;

  auto rdA = [&](int buf, int kk, int mf) -> s16x8 {
    return *(const s16x8*)((const char*)lds + (buf * 49152 + aoffb + mf * 2048 + colx[kk]));
  };
  auto rdB = [&](int buf, int kk, int nf) -> s16x8 {
    return *(const s16x8*)((const char*)lds + (buf * 49152 + boffb + nf * 2048 + colx[kk]));
  };

#define MFMA_ROW2(A0, A1, A2, A3, BB, NF) \
  acc[0][NF] = __builtin_amdgcn_mfma_f32_16x16x32_bf16(A0, BB, acc[0][NF], 0, 0, 0); \
  acc[1][NF] = __builtin_amdgcn_mfma_f32_16x16x32_bf16(A1, BB, acc[1][NF], 0, 0, 0); \
  acc[2][NF] = __builtin_amdgcn_mfma_f32_16x16x32_bf16(A2, BB, acc[2][NF], 0, 0, 0); \
  acc[3][NF] = __builtin_amdgcn_mfma_f32_16x16x32_bf16(A3, BB, acc[3][NF], 0, 0, 0);

  // ---- prologue: stage tiles 0 and 1 ----
#pragma unroll
  for (int it = 0; it < 4; ++it) issueA(0, 0, it);
#pragma unroll
  for (int it = 0; it < 2; ++it) issueB(0, 0, it);
#pragma unroll
  for (int it = 0; it < 4; ++it) issueA(1, 1, it);
#pragma unroll
  for (int it = 0; it < 2; ++it) issueB(1, 1, it);
  asm volatile("s_waitcnt vmcnt(6)" ::: "memory");
  __builtin_amdgcn_sched_barrier(0);
  __builtin_amdgcn_s_barrier();
  __builtin_amdgcn_sched_barrier(0);

  int bR = 0;
  for (int tt = 0; tt <= nt - 3; ++tt) {
    const int bn2 = (bR >= 1) ? bR - 1 : 2;      // (bR+2)%3
    // ---- phase 0: A-frags kk=0, B-frags 0..1; prefetch A slices 0,1 ----
    s16x8 a0 = rdA(bR, 0, 0), a1 = rdA(bR, 0, 1), a2 = rdA(bR, 0, 2), a3 = rdA(bR, 0, 3);
    s16x8 b0 = rdB(bR, 0, 0), b1 = rdB(bR, 0, 1);
    issueA(bn2, tt + 2, 0); issueA(bn2, tt + 2, 1);
    __builtin_amdgcn_s_barrier();
    __builtin_amdgcn_s_setprio(1);
    MFMA_ROW2(a0, a1, a2, a3, b0, 0)
    MFMA_ROW2(a0, a1, a2, a3, b1, 1)
    __builtin_amdgcn_s_setprio(0);
    __builtin_amdgcn_s_barrier();
    // ---- phase 1: B-frags 2..3; prefetch A slices 2,3 ----
    s16x8 b2 = rdB(bR, 0, 2), b3 = rdB(bR, 0, 3);
    issueA(bn2, tt + 2, 2); issueA(bn2, tt + 2, 3);
    __builtin_amdgcn_s_barrier();
    __builtin_amdgcn_s_setprio(1);
    MFMA_ROW2(a0, a1, a2, a3, b2, 2)
    MFMA_ROW2(a0, a1, a2, a3, b3, 3)
    __builtin_amdgcn_s_setprio(0);
    __builtin_amdgcn_s_barrier();
    // ---- phase 2: kk=1 A-frags + B 0..1; prefetch B slice 0 ----
    a0 = rdA(bR, 1, 0); a1 = rdA(bR, 1, 1); a2 = rdA(bR, 1, 2); a3 = rdA(bR, 1, 3);
    b0 = rdB(bR, 1, 0); b1 = rdB(bR, 1, 1);
    issueB(bn2, tt + 2, 0);
    __builtin_amdgcn_s_barrier();
    __builtin_amdgcn_s_setprio(1);
    MFMA_ROW2(a0, a1, a2, a3, b0, 0)
    MFMA_ROW2(a0, a1, a2, a3, b1, 1)
    __builtin_amdgcn_s_setprio(0);
    __builtin_amdgcn_s_barrier();
    // ---- phase 3: B 2..3; prefetch B slice 1; counted vmcnt; publish ----
    b2 = rdB(bR, 1, 2); b3 = rdB(bR, 1, 3);
    issueB(bn2, tt + 2, 1);
    __builtin_amdgcn_s_barrier();
    __builtin_amdgcn_s_setprio(1);
    MFMA_ROW2(a0, a1, a2, a3, b2, 2)
    MFMA_ROW2(a0, a1, a2, a3, b3, 3)
    __builtin_amdgcn_s_setprio(0);
    asm volatile("s_waitcnt vmcnt(6)" ::: "memory");
    __builtin_amdgcn_sched_barrier(0);
    __builtin_amdgcn_s_barrier();
    __builtin_amdgcn_sched_barrier(0);
    bR = (bR == 2) ? 0 : bR + 1;
  }

  // ---- tail: tiles nt-2 (published) and nt-1 (drain) ----
  auto compute_tile = [&](int buf) {
#pragma unroll
    for (int kk = 0; kk < 2; ++kk) {
      s16x8 ta0 = rdA(buf, kk, 0), ta1 = rdA(buf, kk, 1);
      s16x8 ta2 = rdA(buf, kk, 2), ta3 = rdA(buf, kk, 3);
      s16x8 tb0 = rdB(buf, kk, 0), tb1 = rdB(buf, kk, 1);
      s16x8 tb2 = rdB(buf, kk, 2), tb3 = rdB(buf, kk, 3);
      MFMA_ROW2(ta0, ta1, ta2, ta3, tb0, 0)
      MFMA_ROW2(ta0, ta1, ta2, ta3, tb1, 1)
      MFMA_ROW2(ta0, ta1, ta2, ta3, tb2, 2)
      MFMA_ROW2(ta0, ta1, ta2, ta3, tb3, 3)
    }
  };
  compute_tile(bR);
  __syncthreads();
  compute_tile((bR == 2) ? 0 : bR + 1);
#undef MFMA_ROW2

#pragma unroll
  for (int mf = 0; mf < 4; ++mf) {
    int mbase = m0 + wm * 64 + mf * 16 + g * 4;
#pragma unroll
    for (int nf = 0; nf < 4; ++nf) {
      int n = n0 + wn * 64 + nf * 16 + h;
      float bv = bias[n];
#pragma unroll
      for (int qq = 0; qq < 4; ++qq)
        C[(size_t)(mbase + qq) * N + n] = acc[mf][nf][qq] + bv;
    }
  }
}

// ======================= Attention (fp32) ==================================
__global__ __launch_bounds__(256) void attn_kernel(
    const float* __restrict__ u,     // [3][64][512][64]
    const float* __restrict__ pos,   // [2][256][256]
    float* __restrict__ xatt)        // [64][2][256][64]
{
  __shared__ float qs[32][68];
  __shared__ float ks[64][68];
  __shared__ float sc[32][260];
  const int t = threadIdx.x;
  const int rt = blockIdx.x;
  const int cc = blockIdx.y;
  const int b  = blockIdx.z;
  const int i0 = rt * 32;

  const float* Q  = u + ((size_t)(0 * 64 + b) * 512 + cc * 256) * 64;
  const float* Km = u + ((size_t)(1 * 64 + b) * 512 + cc * 256) * 64;
  const float* Vm = u + ((size_t)(2 * 64 + b) * 512 + cc * 256) * 64;

#pragma unroll
  for (int rep = 0; rep < 2; ++rep) {
    int flat = t + rep * 256;
    int r = flat >> 4;
    int kq = (flat & 15) * 4;
    *(float4*)&qs[r][kq] = *(const float4*)(Q + (size_t)(i0 + r) * 64 + kq);
  }

  const int rg = t >> 4;
  const int cg = t & 15;
  const int rg2 = rg * 2;

  for (int chunk = 0; chunk < 4; ++chunk) {
    __syncthreads();
#pragma unroll
    for (int rep = 0; rep < 4; ++rep) {
      int flat = t + rep * 256;
      int jr = flat >> 4; int kq = (flat & 15) * 4;
      *(float4*)&ks[jr][kq] = *(const float4*)(Km + (size_t)(chunk * 64 + jr) * 64 + kq);
    }
    __syncthreads();

    float d2[2][4];
#pragma unroll
    for (int rr = 0; rr < 2; ++rr)
#pragma unroll
      for (int jj = 0; jj < 4; ++jj) d2[rr][jj] = 0.f;

    for (int k4 = 0; k4 < 64; k4 += 4) {
      float4 a0 = *(const float4*)&qs[rg2][k4];
      float4 a1 = *(const float4*)&qs[rg2 + 1][k4];
#pragma unroll
      for (int jj = 0; jj < 4; ++jj) {
        float4 bv = *(const float4*)&ks[cg + 16 * jj][k4];
        d2[0][jj] = fmaf(a0.x, bv.x, fmaf(a0.y, bv.y, fmaf(a0.z, bv.z, fmaf(a0.w, bv.w, d2[0][jj]))));
        d2[1][jj] = fmaf(a1.x, bv.x, fmaf(a1.y, bv.y, fmaf(a1.z, bv.z, fmaf(a1.w, bv.w, d2[1][jj]))));
      }
    }
#pragma unroll
    for (int rr = 0; rr < 2; ++rr)
#pragma unroll
      for (int jj = 0; jj < 4; ++jj) {
        int j = chunk * 64 + cg + 16 * jj;
        int ig = i0 + rg2 + rr;
        sc[rg2 + rr][j] = d2[rr][jj] * 0.125f + pos[((size_t)cc * 256 + ig) * 256 + j];
      }
  }
  __syncthreads();

  {
    const int r = t >> 3;
    const int j8 = t & 7;
    float mx = -3.4e38f;
#pragma unroll
    for (int jj = 0; jj < 32; ++jj) mx = fmaxf(mx, sc[r][j8 + 8 * jj]);
#pragma unroll
    for (int mset = 1; mset < 8; mset <<= 1) mx = fmaxf(mx, __shfl_xor(mx, mset, 64));
    float sum = 0.f;
#pragma unroll
    for (int jj = 0; jj < 32; ++jj) {
      float e = expf(sc[r][j8 + 8 * jj] - mx);
      sc[r][j8 + 8 * jj] = e;
      sum += e;
    }
#pragma unroll
    for (int mset = 1; mset < 8; mset <<= 1) sum += __shfl_xor(sum, mset, 64);
    float inv = 1.f / sum;
#pragma unroll
    for (int jj = 0; jj < 32; ++jj) sc[r][j8 + 8 * jj] *= inv;
  }

  f32x4 oacc[2];
  oacc[0] = (f32x4){0.f, 0.f, 0.f, 0.f};
  oacc[1] = (f32x4){0.f, 0.f, 0.f, 0.f};

  for (int chunk = 0; chunk < 4; ++chunk) {
    __syncthreads();
#pragma unroll
    for (int rep = 0; rep < 4; ++rep) {
      int flat = t + rep * 256;
      int jr = flat >> 4; int kq = (flat & 15) * 4;
      *(float4*)&ks[jr][kq] = *(const float4*)(Vm + (size_t)(chunk * 64 + jr) * 64 + kq);
    }
    __syncthreads();
    for (int jl = 0; jl < 64; ++jl) {
      float p0 = sc[rg2][chunk * 64 + jl];
      float p1 = sc[rg2 + 1][chunk * 64 + jl];
      f32x4 vv = *(const f32x4*)&ks[jl][cg * 4];
#pragma unroll
      for (int kk = 0; kk < 4; ++kk) {
        oacc[0][kk] = fmaf(p0, vv[kk], oacc[0][kk]);
        oacc[1][kk] = fmaf(p1, vv[kk], oacc[1][kk]);
      }
    }
  }
#pragma unroll
  for (int rr = 0; rr < 2; ++rr) {
    float* O = xatt + ((size_t)(b * 2 + cc) * 256 + i0 + rg2 + rr) * 64;
    *(f32x4*)&O[cg * 4] = oacc[rr];
  }
}

// ======================= rearrange + conv1d -> y1' bf16 hi|lo ==============
__global__ __launch_bounds__(512) void conv1d_kernel(
    const float* __restrict__ xatt, const float* __restrict__ w,
    const float* __restrict__ bias, unsigned short* __restrict__ y1p)
{
  __shared__ float X[16][520];
  __shared__ float W[512];
  __shared__ float Bp[32];
  const int t = threadIdx.x;       // 0..511
  const int lt = blockIdx.x;       // 0..3
  const int b  = blockIdx.y;       // 0..63
  if (t < 512) W[t] = w[t];
  if (t < 32) Bp[t] = bias[t];
#pragma unroll
  for (int cc = 0; cc < 2; ++cc) {
    const float* src = xatt + ((size_t)(b * 2 + cc) * 256 + lt * 64) * 64;
#pragma unroll
    for (int pass = 0; pass < 2; ++pass) {
      int f4 = t + pass * 512;
      float4 v4 = *(const float4*)(src + (size_t)f4 * 4);
      int fl = f4 * 4;
      int dl = fl >> 6;
      int rr = fl & 63;
      int p1 = rr >> 3, p2 = rr & 7;
      *(float4*)&X[cc * 8 + p1][dl * 8 + p2] = v4;
    }
  }
  __syncthreads();

  float xv[16];
#pragma unroll
  for (int ch = 0; ch < 16; ++ch) xv[ch] = X[ch][t];

  size_t obase = (size_t)b * 32 * 4096 + lt * 512 + t;
#pragma unroll
  for (int o = 0; o < 32; ++o) {
    float s = Bp[o];
#pragma unroll
    for (int ch = 0; ch < 16; ++ch) s = fmaf(xv[ch], W[o * 16 + ch], s);
    unsigned short hi = f2bf(s);
    unsigned short lo = f2bf(s - bf2f(hi));
    y1p[obase + (size_t)o * 4096] = hi;
    y1p[obase + (size_t)o * 4096 + 2048] = lo;
  }
}

// ======================= launch ============================================
extern "C" void kernel_launch(void* const* d_in, const int* in_sizes, int n_in,
                              void* d_out, int out_size, void* d_ws, size_t ws_size,
                              hipStream_t stream) {
  const float* q    = (const float*)d_in[0];
  const float* k    = (const float*)d_in[1];
  const float* v    = (const float*)d_in[2];
  const float* dwk  = (const float*)d_in[3];
  const float* bng  = (const float*)d_in[4];
  const float* bnb  = (const float*)d_in[5];
  const float* bnm  = (const float*)d_in[6];
  const float* bnv  = (const float*)d_in[7];
  const float* pwk  = (const float*)d_in[8];
  const float* pos  = (const float*)d_in[9];
  const float* c1w  = (const float*)d_in[10];
  const float* c1b  = (const float*)d_in[11];
  const float* linw = (const float*)d_in[12];
  const float* linb = (const float*)d_in[13];
  float* out = (float*)d_out;

  if (ws_size < 50331648u) return;

  char* ws = (char*)d_ws;
  float*          u    = (float*)(ws + 0);                   // 25,165,824 B
  unsigned short* tTp  = (unsigned short*)(ws + 25165824);   // 12,582,912 B
  unsigned short* pwkp = (unsigned short*)(ws + 37748736);   //  1,048,576 B
  float*          xatt = (float*)(ws + 25165824);            //  8,388,608 B
  unsigned short* y1p  = (unsigned short*)(ws + 0);          // 16,777,216 B
  unsigned short* lwp  = (unsigned short*)(ws + 16777216);   // 33,554,432 B

  for (int i = 0; i < 3; ++i) {
    const float* x = (i == 0) ? q : (i == 1) ? k : v;
    stageA_kernel<<<1024, 256, 0, stream>>>(
        x, dwk + (size_t)i * 512 * 9, bng + i * 512, bnb + i * 512,
        bnm + i * 512, bnv + i * 512, tTp);
    split_kernel<<<256, 256, 0, stream>>>(pwk + (size_t)i * 512 * 512, pwkp, 9, 65536);
    dim3 g1(32, 8);
    gemm_split_kernel<<<g1, 256, 0, stream>>>(
        pwkp, tTp, u + (size_t)i * 2097152, 512, 4096, 512);
  }

  dim3 g2(8, 2, 64);
  attn_kernel<<<g2, 256, 0, stream>>>(u, pos, xatt);

  conv1d_kernel<<<dim3(4, 64), 512, 0, stream>>>(xatt, c1w, c1b, y1p);

  split_kernel<<<8192, 256, 0, stream>>>(linw, lwp, 11, 2097152);

  dim3 g3(32, 8);   // MUST stay (32,8): swizzle shifts hardcoded
  gemm_pipe_kernel<<<g3, 512, 0, stream>>>(y1p, lwp, out, linb, 2048, 4096, 2048);
}

// Round 6
// 260.278 us; speedup vs baseline: 2.9216x; 1.1534x over previous
//
#include <hip/hip_runtime.h>

// ---------------------------------------------------------------------------
// Geometry: b=64, units=32, d_model=4096, P=16 -> c=2, d=256, C=512,
// dwconv 3x3 s2 16x16->8x8 (hw=64), dk=64; attn 256x256 per (b,cc);
// conv1d 16->32 over l=2048; linear 2048->4096.
//
// All GEMM-shaped work (pointwise, attention QK^T/PV, final linear) runs as
// bf16 hi/lo split MFMA:  C = Ah*Bh + Ah*Bl + Al*Bh  (error ~2^-17 rel).
//
// Workspace (bytes), ws >= 50331648:
//   phase1: q'  bf16 [128][256][128] @ 0           (8,388,608)
//           k'  bf16 [128][256][128] @ 8,388,608   (8,388,608)
//           vt' bf16 [128][64][512]  @ 16,777,216  (8,388,608)
//           tTp bf16 [4096][1024]    @ 25,165,824  (12,582,912)
//           pwkp bf16 [3][512][1024] @ 37,748,736  (3,145,728)
//   phase2: xatt fp32 [64][2][256][64] @ 25,165,824 (8,388,608)
//   phase3: y1' bf16 [2048][4096]    @ 0           (16,777,216)
//           linw' bf16 [4096][4096]  @ 16,777,216  (33,554,432)
// ---------------------------------------------------------------------------

typedef short s16x8 __attribute__((ext_vector_type(8)));
typedef float f32x4 __attribute__((ext_vector_type(4)));
typedef const __attribute__((address_space(1))) void* gas_t;
typedef __attribute__((address_space(3))) void* las_t;

__device__ __forceinline__ unsigned short f2bf(float x) {
  unsigned u = __float_as_uint(x);
  unsigned r = u + 0x7fffu + ((u >> 16) & 1u);
  return (unsigned short)(r >> 16);
}
__device__ __forceinline__ float bf2f(unsigned short h) {
  return __uint_as_float((unsigned)h << 16);
}

// ======================= Stage A: patch + dwconv + BN + GELU ===============
__global__ __launch_bounds__(256) void stageA_kernel(
    const float* __restrict__ x, const float* __restrict__ dwk_i,
    const float* __restrict__ bng, const float* __restrict__ bnb,
    const float* __restrict__ bnm, const float* __restrict__ bnv,
    unsigned short* __restrict__ tTp)
{
  const int dd = threadIdx.x;              // 0..255
  const int oh = blockIdx.x & 7;
  const int cc = (blockIdx.x >> 3) & 1;
  const int b  = blockIdx.x >> 4;
  const int ch = cc * 256 + dd;

  float r[3][16];
#pragma unroll
  for (int kh = 0; kh < 3; ++kh) {
    int ih = 2 * oh - 1 + kh;
    if (ih >= 0 && ih <= 15) {
      const float* p = x + (size_t)(b * 32 + cc * 16 + ih) * 4096 + dd * 16;
#pragma unroll
      for (int jq = 0; jq < 4; ++jq)
        *(float4*)&r[kh][jq * 4] = *(const float4*)(p + jq * 4);
    } else {
#pragma unroll
      for (int j = 0; j < 16; ++j) r[kh][j] = 0.f;
    }
  }
  float w9[9];
#pragma unroll
  for (int j = 0; j < 9; ++j) w9[j] = dwk_i[ch * 9 + j];
  const float scale = bng[ch] / sqrtf(bnv[ch] + 1e-5f);
  const float shift = bnb[ch] - bnm[ch] * scale;

#pragma unroll
  for (int ow = 0; ow < 8; ++ow) {
    float acc = 0.f;
#pragma unroll
    for (int kh = 0; kh < 3; ++kh)
#pragma unroll
      for (int kw = 0; kw < 3; ++kw) {
        int iw = 2 * ow - 1 + kw;
        if (iw >= 0 && iw <= 15) acc = fmaf(r[kh][iw], w9[kh * 3 + kw], acc);
      }
    float y = acc * scale + shift;
    y = 0.5f * y * (1.f + erff(y * 0.70710678118654752f));
    unsigned short hi = f2bf(y);
    unsigned short lo = f2bf(y - bf2f(hi));
    size_t rowb = (size_t)(b * 64 + oh * 8 + ow) * 1024;
    tTp[rowb + ch] = hi;
    tTp[rowb + 512 + ch] = lo;
  }
}

// ======================= fp32 -> bf16 hi|lo split ==========================
__global__ __launch_bounds__(256) void split_kernel(
    const float* __restrict__ src, unsigned short* __restrict__ dst,
    int kshift, int total4)
{
  int i = blockIdx.x * 256 + threadIdx.x;
  if (i >= total4) return;
  size_t i4 = (size_t)i * 4;
  int K = 1 << kshift;
  int r = (int)(i4 >> kshift);
  int c = (int)(i4 & (size_t)(K - 1));
  float4 xv = *(const float4*)(src + i4);
  unsigned short h0 = f2bf(xv.x), h1 = f2bf(xv.y), h2 = f2bf(xv.z), h3 = f2bf(xv.w);
  unsigned short l0 = f2bf(xv.x - bf2f(h0)), l1 = f2bf(xv.y - bf2f(h1));
  unsigned short l2 = f2bf(xv.z - bf2f(h2)), l3 = f2bf(xv.w - bf2f(h3));
  unsigned short* dr = dst + (size_t)r * (K * 2) + c;
  uint2 hp, lp;
  hp.x = (unsigned)h0 | ((unsigned)h1 << 16);
  hp.y = (unsigned)h2 | ((unsigned)h3 << 16);
  lp.x = (unsigned)l0 | ((unsigned)l1 << 16);
  lp.y = (unsigned)l2 | ((unsigned)l3 << 16);
  *(uint2*)dr = hp;
  *(uint2*)(dr + K) = lp;
}

// ======================= pointwise: bf16-split MFMA NT GEMM ================
// BM=64 x 128 tile, 4 waves 1x4. C = pwk_i * tT^T, written as split-bf16:
// mode 0/1 (Q/K): Cq[((b*2+cc)*256 + ch%256)*128 + d (+64 lo)]
// mode 2    (V) : Cq[((b*2+cc)*64 + d)*512 + ch%256 (+256 lo)]   (transposed)
__global__ __launch_bounds__(256) void gemm_split_kernel(
    const unsigned short* __restrict__ A, const unsigned short* __restrict__ B,
    unsigned short* __restrict__ Cq, int M, int N, int K, int mode)
{
  __shared__ unsigned short sA[4096];    // [64][64]
  __shared__ unsigned short sB[8192];    // [128][64]
  const int t = threadIdx.x;
  const int m0 = blockIdx.y * 64, n0 = blockIdx.x * 128;
  const int Kp = 3 * K, twoK = 2 * K, Km = K - 1;
  const int lane = t & 63;
  const int wv = t >> 6;
  const int colbase = wv * 32;
  const int h = lane & 15, g = lane >> 4;

  f32x4 acc[4][2];
#pragma unroll
  for (int mf = 0; mf < 4; ++mf)
#pragma unroll
    for (int nf = 0; nf < 2; ++nf)
      acc[mf][nf] = (f32x4){0.f, 0.f, 0.f, 0.f};

  int srow[4], sblk[4];
#pragma unroll
  for (int it = 0; it < 4; ++it) {
    int s = it * 256 + t;
    srow[it] = s >> 3;
    sblk[it] = (s & 7) ^ (srow[it] & 7);
  }
  const int ldsw = (t & 192) << 4;

  for (int k0 = 0; k0 < Kp; k0 += 64) {
    __syncthreads();
#pragma unroll
    for (int it = 0; it < 2; ++it) {
      int kp = k0 + sblk[it] * 8;
      int ac = (kp < twoK) ? (kp & Km) : (kp - K);
      const unsigned short* ga = A + (size_t)(m0 + srow[it]) * twoK + ac;
      __builtin_amdgcn_global_load_lds((gas_t)(const void*)ga,
          (las_t)(void*)((char*)sA + (it * 4096 + ldsw)), 16, 0, 0);
    }
#pragma unroll
    for (int it = 0; it < 4; ++it) {
      int kp = k0 + sblk[it] * 8;
      int bc = (kp < twoK) ? kp : (kp - twoK);
      const unsigned short* gb = B + (size_t)(n0 + srow[it]) * twoK + bc;
      __builtin_amdgcn_global_load_lds((gas_t)(const void*)gb,
          (las_t)(void*)((char*)sB + (it * 4096 + ldsw)), 16, 0, 0);
    }
    __syncthreads();

#pragma unroll
    for (int kk = 0; kk < 2; ++kk) {
      s16x8 af[4], bfr[2];
#pragma unroll
      for (int mf = 0; mf < 4; ++mf) {
        int arow = mf * 16 + h;
        int aoff = arow * 128 + (((kk * 4 + g) ^ (h & 7)) << 4);
        af[mf] = *(const s16x8*)((const char*)sA + aoff);
      }
#pragma unroll
      for (int nf = 0; nf < 2; ++nf) {
        int brow = colbase + nf * 16 + h;
        int boff = brow * 128 + (((kk * 4 + g) ^ (h & 7)) << 4);
        bfr[nf] = *(const s16x8*)((const char*)sB + boff);
      }
#pragma unroll
      for (int mf = 0; mf < 4; ++mf)
#pragma unroll
        for (int nf = 0; nf < 2; ++nf)
          acc[mf][nf] = __builtin_amdgcn_mfma_f32_16x16x32_bf16(
              af[mf], bfr[nf], acc[mf][nf], 0, 0, 0);
    }
  }

  if (mode < 2) {
    // Q'/K' layout: rows = attention row index (ch%256), cols = d hi|lo
#pragma unroll
    for (int mf = 0; mf < 4; ++mf) {
      int mbase = m0 + mf * 16 + g * 4;
#pragma unroll
      for (int nf = 0; nf < 2; ++nf) {
        int n = n0 + colbase + nf * 16 + h;
        int bb = n >> 6, d = n & 63;
#pragma unroll
        for (int qq = 0; qq < 4; ++qq) {
          int m = mbase + qq;
          int cc = m >> 8;
          size_t rowb = ((size_t)(bb * 2 + cc) * 256 + (m & 255)) * 128;
          float vvv = acc[mf][nf][qq];
          unsigned short hi = f2bf(vvv);
          unsigned short lo = f2bf(vvv - bf2f(hi));
          Cq[rowb + d] = hi;
          Cq[rowb + 64 + d] = lo;
        }
      }
    }
  } else {
    // V^T layout: rows = d, cols = j hi|lo ; qq -> 4 consecutive j
#pragma unroll
    for (int mf = 0; mf < 4; ++mf) {
      int mbase = m0 + mf * 16 + g * 4;
      int cc = mbase >> 8;
      int mc = mbase & 255;
#pragma unroll
      for (int nf = 0; nf < 2; ++nf) {
        int n = n0 + colbase + nf * 16 + h;
        int bb = n >> 6, d = n & 63;
        size_t rowb = ((size_t)(bb * 2 + cc) * 64 + d) * 512;
        ushort4 hv, lv;
        float v0 = acc[mf][nf][0], v1 = acc[mf][nf][1];
        float v2 = acc[mf][nf][2], v3 = acc[mf][nf][3];
        hv.x = f2bf(v0); hv.y = f2bf(v1); hv.z = f2bf(v2); hv.w = f2bf(v3);
        lv.x = f2bf(v0 - bf2f(hv.x)); lv.y = f2bf(v1 - bf2f(hv.y));
        lv.z = f2bf(v2 - bf2f(hv.z)); lv.w = f2bf(v3 - bf2f(hv.w));
        *(ushort4*)&Cq[rowb + mc] = hv;
        *(ushort4*)&Cq[rowb + 256 + mc] = lv;
      }
    }
  }
}

// ======================= final linear: deep-pipelined split GEMM ===========
// BM=256, BN=128, BK=64, 8 waves, 3 LDS buffers, counted vmcnt(6).
// Launched with grid (32, 8) ONLY (hardcoded swizzle).
__global__ __launch_bounds__(512, 2) void gemm_pipe_kernel(
    const unsigned short* __restrict__ A, const unsigned short* __restrict__ B,
    float* __restrict__ C, const float* __restrict__ bias,
    int M, int N, int K)
{
  __shared__ unsigned short lds[73728];    // 147456 B = 3 x 49152
  const int t = threadIdx.x;

  // T1: XCD chunk swizzle, 4m x 8n tiles per XCD (XCD = flat%8)
  const int flat = blockIdx.y * 32 + blockIdx.x;
  const int xcd = flat & 7;
  const int ii = flat >> 3;
  const int mt = (xcd >> 2) * 4 + (ii >> 3);
  const int ntile = (xcd & 3) * 8 + (ii & 7);
  const int m0 = mt * 256;
  const int n0 = ntile * 128;

  const int twoK = 2 * K, Km = K - 1;
  const int nt = (3 * K) >> 6;             // K-tiles (>= 3)

  const int lane = t & 63;
  const int wv = t >> 6;
  const int wm = wv & 3, wn = wv >> 2;
  const int h = lane & 15, g = lane >> 4;

  f32x4 acc[4][4];
#pragma unroll
  for (int mf = 0; mf < 4; ++mf)
#pragma unroll
    for (int nf = 0; nf < 4; ++nf)
      acc[mf][nf] = (f32x4){0.f, 0.f, 0.f, 0.f};

  int arow[4], ablk[4], brow[2], bblk[2];
#pragma unroll
  for (int it = 0; it < 4; ++it) {
    int s = it * 512 + t;
    arow[it] = s >> 3;
    ablk[it] = (t & 7) ^ (arow[it] & 7);
  }
#pragma unroll
  for (int it = 0; it < 2; ++it) {
    int s = it * 512 + t;
    brow[it] = s >> 3;
    bblk[it] = (t & 7) ^ (brow[it] & 7);
  }

  auto issueA = [&](int buf, int tt, int it) {
    int kp = tt * 64 + ablk[it] * 8;
    int ac = (kp < twoK) ? (kp & Km) : (kp - K);
    __builtin_amdgcn_global_load_lds(
        (gas_t)(const void*)(A + (size_t)(m0 + arow[it]) * twoK + ac),
        (las_t)(void*)((char*)lds + (buf * 49152 + it * 8192 + t * 16)), 16, 0, 0);
  };
  auto issueB = [&](int buf, int tt, int it) {
    int kp = tt * 64 + bblk[it] * 8;
    int bc = (kp < twoK) ? kp : (kp - twoK);
    __builtin_amdgcn_global_load_lds(
        (gas_t)(const void*)(B + (size_t)(n0 + brow[it]) * twoK + bc),
        (las_t)(void*)((char*)lds + (buf * 49152 + 32768 + it * 8192 + t * 16)), 16, 0, 0);
  };

  const int aoffb = (wm * 64 + h) * 128;
  const int boffb = 32768 + (wn * 64 + h) * 128;
  int colx[2];
  colx[0] = ((g) ^ (h & 7)) << 4;
  colx[1] = ((4 + g) ^ (h & 7)) << 4;

  auto rdA = [&](int buf, int kk, int mf) -> s16x8 {
    return *(const s16x8*)((const char*)lds + (buf * 49152 + aoffb + mf * 2048 + colx[kk]));
  };
  auto rdB = [&](int buf, int kk, int nf) -> s16x8 {
    return *(const s16x8*)((const char*)lds + (buf * 49152 + boffb + nf * 2048 + colx[kk]));
  };

#define MFMA_ROW2(A0, A1, A2, A3, BB, NF) \
  acc[0][NF] = __builtin_amdgcn_mfma_f32_16x16x32_bf16(A0, BB, acc[0][NF], 0, 0, 0); \
  acc[1][NF] = __builtin_amdgcn_mfma_f32_16x16x32_bf16(A1, BB, acc[1][NF], 0, 0, 0); \
  acc[2][NF] = __builtin_amdgcn_mfma_f32_16x16x32_bf16(A2, BB, acc[2][NF], 0, 0, 0); \
  acc[3][NF] = __builtin_amdgcn_mfma_f32_16x16x32_bf16(A3, BB, acc[3][NF], 0, 0, 0);

  // ---- prologue: stage tiles 0 and 1 ----
#pragma unroll
  for (int it = 0; it < 4; ++it) issueA(0, 0, it);
#pragma unroll
  for (int it = 0; it < 2; ++it) issueB(0, 0, it);
#pragma unroll
  for (int it = 0; it < 4; ++it) issueA(1, 1, it);
#pragma unroll
  for (int it = 0; it < 2; ++it) issueB(1, 1, it);
  asm volatile("s_waitcnt vmcnt(6)" ::: "memory");
  __builtin_amdgcn_sched_barrier(0);
  __builtin_amdgcn_s_barrier();
  __builtin_amdgcn_sched_barrier(0);

  int bR = 0;
  for (int tt = 0; tt <= nt - 3; ++tt) {
    const int bn2 = (bR >= 1) ? bR - 1 : 2;      // (bR+2)%3
    s16x8 a0 = rdA(bR, 0, 0), a1 = rdA(bR, 0, 1), a2 = rdA(bR, 0, 2), a3 = rdA(bR, 0, 3);
    s16x8 b0 = rdB(bR, 0, 0), b1 = rdB(bR, 0, 1);
    issueA(bn2, tt + 2, 0); issueA(bn2, tt + 2, 1);
    __builtin_amdgcn_s_barrier();
    __builtin_amdgcn_s_setprio(1);
    MFMA_ROW2(a0, a1, a2, a3, b0, 0)
    MFMA_ROW2(a0, a1, a2, a3, b1, 1)
    __builtin_amdgcn_s_setprio(0);
    __builtin_amdgcn_s_barrier();
    s16x8 b2 = rdB(bR, 0, 2), b3 = rdB(bR, 0, 3);
    issueA(bn2, tt + 2, 2); issueA(bn2, tt + 2, 3);
    __builtin_amdgcn_s_barrier();
    __builtin_amdgcn_s_setprio(1);
    MFMA_ROW2(a0, a1, a2, a3, b2, 2)
    MFMA_ROW2(a0, a1, a2, a3, b3, 3)
    __builtin_amdgcn_s_setprio(0);
    __builtin_amdgcn_s_barrier();
    a0 = rdA(bR, 1, 0); a1 = rdA(bR, 1, 1); a2 = rdA(bR, 1, 2); a3 = rdA(bR, 1, 3);
    b0 = rdB(bR, 1, 0); b1 = rdB(bR, 1, 1);
    issueB(bn2, tt + 2, 0);
    __builtin_amdgcn_s_barrier();
    __builtin_amdgcn_s_setprio(1);
    MFMA_ROW2(a0, a1, a2, a3, b0, 0)
    MFMA_ROW2(a0, a1, a2, a3, b1, 1)
    __builtin_amdgcn_s_setprio(0);
    __builtin_amdgcn_s_barrier();
    b2 = rdB(bR, 1, 2); b3 = rdB(bR, 1, 3);
    issueB(bn2, tt + 2, 1);
    __builtin_amdgcn_s_barrier();
    __builtin_amdgcn_s_setprio(1);
    MFMA_ROW2(a0, a1, a2, a3, b2, 2)
    MFMA_ROW2(a0, a1, a2, a3, b3, 3)
    __builtin_amdgcn_s_setprio(0);
    asm volatile("s_waitcnt vmcnt(6)" ::: "memory");
    __builtin_amdgcn_sched_barrier(0);
    __builtin_amdgcn_s_barrier();
    __builtin_amdgcn_sched_barrier(0);
    bR = (bR == 2) ? 0 : bR + 1;
  }

  auto compute_tile = [&](int buf) {
#pragma unroll
    for (int kk = 0; kk < 2; ++kk) {
      s16x8 ta0 = rdA(buf, kk, 0), ta1 = rdA(buf, kk, 1);
      s16x8 ta2 = rdA(buf, kk, 2), ta3 = rdA(buf, kk, 3);
      s16x8 tb0 = rdB(buf, kk, 0), tb1 = rdB(buf, kk, 1);
      s16x8 tb2 = rdB(buf, kk, 2), tb3 = rdB(buf, kk, 3);
      MFMA_ROW2(ta0, ta1, ta2, ta3, tb0, 0)
      MFMA_ROW2(ta0, ta1, ta2, ta3, tb1, 1)
      MFMA_ROW2(ta0, ta1, ta2, ta3, tb2, 2)
      MFMA_ROW2(ta0, ta1, ta2, ta3, tb3, 3)
    }
  };
  compute_tile(bR);
  __syncthreads();
  compute_tile((bR == 2) ? 0 : bR + 1);
#undef MFMA_ROW2

#pragma unroll
  for (int mf = 0; mf < 4; ++mf) {
    int mbase = m0 + wm * 64 + mf * 16 + g * 4;
#pragma unroll
    for (int nf = 0; nf < 4; ++nf) {
      int n = n0 + wn * 64 + nf * 16 + h;
      float bv = bias[n];
#pragma unroll
      for (int qq = 0; qq < 4; ++qq)
        C[(size_t)(mbase + qq) * N + n] = acc[mf][nf][qq] + bv;
    }
  }
}

// ======================= Attention (MFMA, split bf16) ======================
// Block = (rt, cc, b): 32 query rows, 256 thr (4 waves).
// LDS: qs [32][136] bf16 @0 (8704 B); kv [64][136] bf16 @8704 (17408 B);
//      sc fp32 [32][264] / ps bf16 [32][528] overlay @26112 (33792 B).
__global__ __launch_bounds__(256) void attn_mfma_kernel(
    const unsigned short* __restrict__ qp, const unsigned short* __restrict__ kp,
    const unsigned short* __restrict__ vtp, const float* __restrict__ pos,
    float* __restrict__ xatt)
{
  __shared__ char smem[59904];
  unsigned short* qs = (unsigned short*)smem;
  unsigned short* kv = (unsigned short*)(smem + 8704);
  float* sc = (float*)(smem + 26112);
  unsigned short* ps = (unsigned short*)(smem + 26112);

  const int t = threadIdx.x;
  const int rt = blockIdx.x, cc = blockIdx.y, b = blockIdx.z;
  const int i0 = rt * 32;
  const size_t qkbase = (size_t)(b * 2 + cc) * 256;
  const size_t vbase  = (size_t)(b * 2 + cc) * 64;

  const int lane = t & 63, wvv = t >> 6;
  const int h = lane & 15, g = lane >> 4;

  // ---- stage Q tile (32 rows x 128 split cols = 512 int4, 2 passes) ----
#pragma unroll
  for (int rep = 0; rep < 2; ++rep) {
    int s = t + rep * 256;           // 0..511
    int row = s >> 4;                // 0..31
    int blk = s & 15;                // 0..15
    int4 val = *(const int4*)(qp + (qkbase + i0 + row) * 128 + blk * 8);
    *(int4*)((char*)qs + row * 272 + blk * 16) = val;
  }

  // ---- S phase: 4 chunks of 64 cols ----
  for (int c = 0; c < 4; ++c) {
    __syncthreads();
#pragma unroll
    for (int p2 = 0; p2 < 4; ++p2) {
      int s = t + p2 * 256;          // 0..1023
      int row = s >> 4;              // 0..63
      int blk = s & 15;              // 0..15
      int4 val = *(const int4*)(kp + (qkbase + c * 64 + row) * 128 + blk * 8);
      *(int4*)((char*)kv + row * 272 + blk * 16) = val;
    }
    __syncthreads();
    f32x4 acc2[2];
    acc2[0] = (f32x4){0.f, 0.f, 0.f, 0.f};
    acc2[1] = (f32x4){0.f, 0.f, 0.f, 0.f};
#pragma unroll
    for (int kk = 0; kk < 6; ++kk) {
      int abase = (kk < 2) ? kk * 32 : (kk < 4) ? 64 + (kk - 2) * 32 : (kk - 4) * 32;
      int bbase = (kk < 2) ? kk * 32 : (kk < 4) ? (kk - 2) * 32 : 64 + (kk - 4) * 32;
      s16x8 bfrag = *(const s16x8*)((char*)kv + (wvv * 16 + h) * 272 + (bbase + g * 8) * 2);
#pragma unroll
      for (int mf = 0; mf < 2; ++mf) {
        s16x8 afrag = *(const s16x8*)((char*)qs + (mf * 16 + h) * 272 + (abase + g * 8) * 2);
        acc2[mf] = __builtin_amdgcn_mfma_f32_16x16x32_bf16(afrag, bfrag, acc2[mf], 0, 0, 0);
      }
    }
#pragma unroll
    for (int mf = 0; mf < 2; ++mf)
#pragma unroll
      for (int qq = 0; qq < 4; ++qq) {
        int row = mf * 16 + g * 4 + qq;
        int j = c * 64 + wvv * 16 + h;
        sc[row * 264 + j] = acc2[mf][qq] * 0.125f +
            pos[((size_t)cc * 256 + i0 + row) * 256 + j];
      }
  }
  __syncthreads();

  // ---- softmax (fp32, 8 threads/row) + in-place P split-bf16 write ----
  {
    const int r = t >> 3, j8 = t & 7;
    float e[32];
    float mx = -3.4e38f;
#pragma unroll
    for (int jj = 0; jj < 32; ++jj) {
      e[jj] = sc[r * 264 + j8 + 8 * jj];
      mx = fmaxf(mx, e[jj]);
    }
#pragma unroll
    for (int mset = 1; mset < 8; mset <<= 1) mx = fmaxf(mx, __shfl_xor(mx, mset, 64));
    float sum = 0.f;
#pragma unroll
    for (int jj = 0; jj < 32; ++jj) {
      e[jj] = expf(e[jj] - mx);
      sum += e[jj];
    }
#pragma unroll
    for (int mset = 1; mset < 8; mset <<= 1) sum += __shfl_xor(sum, mset, 64);
    float inv = 1.f / sum;
    __syncthreads();   // all sc reads done before bf16 overlay writes
#pragma unroll
    for (int jj = 0; jj < 32; ++jj) {
      float pv = e[jj] * inv;
      unsigned short hi = f2bf(pv);
      unsigned short lo = f2bf(pv - bf2f(hi));
      int j = j8 + 8 * jj;
      ps[r * 528 + j] = hi;
      ps[r * 528 + 264 + j] = lo;
    }
  }

  // ---- PV: O[32][64] += P[32][j-chunk] * Vt[d][j-chunk] ----
  f32x4 oacc[2];
  oacc[0] = (f32x4){0.f, 0.f, 0.f, 0.f};
  oacc[1] = (f32x4){0.f, 0.f, 0.f, 0.f};
  for (int c = 0; c < 4; ++c) {
    __syncthreads();
#pragma unroll
    for (int p2 = 0; p2 < 4; ++p2) {
      int s = t + p2 * 256, row = s >> 4, blk = s & 15;
      int col = (blk < 8) ? (c * 64 + blk * 8) : (256 + c * 64 + (blk - 8) * 8);
      int4 val = *(const int4*)(vtp + (vbase + row) * 512 + col);
      *(int4*)((char*)kv + row * 272 + blk * 16) = val;
    }
    __syncthreads();
#pragma unroll
    for (int kk = 0; kk < 6; ++kk) {
      int abase = (kk < 2) ? (c * 64 + kk * 32)
                : (kk < 4) ? (264 + c * 64 + (kk - 2) * 32)
                           : (c * 64 + (kk - 4) * 32);
      int bbase = (kk < 2) ? kk * 32 : (kk < 4) ? (kk - 2) * 32 : 64 + (kk - 4) * 32;
      s16x8 bfrag = *(const s16x8*)((char*)kv + (wvv * 16 + h) * 272 + (bbase + g * 8) * 2);
#pragma unroll
      for (int mf = 0; mf < 2; ++mf) {
        s16x8 afrag = *(const s16x8*)((char*)ps + (mf * 16 + h) * 1056 + (abase + g * 8) * 2);
        oacc[mf] = __builtin_amdgcn_mfma_f32_16x16x32_bf16(afrag, bfrag, oacc[mf], 0, 0, 0);
      }
    }
  }
#pragma unroll
  for (int mf = 0; mf < 2; ++mf)
#pragma unroll
    for (int qq = 0; qq < 4; ++qq) {
      int row = mf * 16 + g * 4 + qq;
      int d = wvv * 16 + h;
      xatt[((size_t)(b * 2 + cc) * 256 + i0 + row) * 64 + d] = oacc[mf][qq];
    }
}

// ======================= rearrange + conv1d -> y1' bf16 hi|lo ==============
__global__ __launch_bounds__(512) void conv1d_kernel(
    const float* __restrict__ xatt, const float* __restrict__ w,
    const float* __restrict__ bias, unsigned short* __restrict__ y1p)
{
  __shared__ float X[16][520];
  __shared__ float W[512];
  __shared__ float Bp[32];
  const int t = threadIdx.x;       // 0..511
  const int lt = blockIdx.x;       // 0..3
  const int b  = blockIdx.y;       // 0..63
  if (t < 512) W[t] = w[t];
  if (t < 32) Bp[t] = bias[t];
#pragma unroll
  for (int cc = 0; cc < 2; ++cc) {
    const float* src = xatt + ((size_t)(b * 2 + cc) * 256 + lt * 64) * 64;
#pragma unroll
    for (int pass = 0; pass < 2; ++pass) {
      int f4 = t + pass * 512;
      float4 v4 = *(const float4*)(src + (size_t)f4 * 4);
      int fl = f4 * 4;
      int dl = fl >> 6;
      int rr = fl & 63;
      int p1 = rr >> 3, p2 = rr & 7;
      *(float4*)&X[cc * 8 + p1][dl * 8 + p2] = v4;
    }
  }
  __syncthreads();

  float xv[16];
#pragma unroll
  for (int ch = 0; ch < 16; ++ch) xv[ch] = X[ch][t];

  size_t obase = (size_t)b * 32 * 4096 + lt * 512 + t;
#pragma unroll
  for (int o = 0; o < 32; ++o) {
    float s = Bp[o];
#pragma unroll
    for (int ch = 0; ch < 16; ++ch) s = fmaf(xv[ch], W[o * 16 + ch], s);
    unsigned short hi = f2bf(s);
    unsigned short lo = f2bf(s - bf2f(hi));
    y1p[obase + (size_t)o * 4096] = hi;
    y1p[obase + (size_t)o * 4096 + 2048] = lo;
  }
}

// ======================= launch ============================================
extern "C" void kernel_launch(void* const* d_in, const int* in_sizes, int n_in,
                              void* d_out, int out_size, void* d_ws, size_t ws_size,
                              hipStream_t stream) {
  const float* q    = (const float*)d_in[0];
  const float* k    = (const float*)d_in[1];
  const float* v    = (const float*)d_in[2];
  const float* dwk  = (const float*)d_in[3];
  const float* bng  = (const float*)d_in[4];
  const float* bnb  = (const float*)d_in[5];
  const float* bnm  = (const float*)d_in[6];
  const float* bnv  = (const float*)d_in[7];
  const float* pwk  = (const float*)d_in[8];
  const float* pos  = (const float*)d_in[9];
  const float* c1w  = (const float*)d_in[10];
  const float* c1b  = (const float*)d_in[11];
  const float* linw = (const float*)d_in[12];
  const float* linb = (const float*)d_in[13];
  float* out = (float*)d_out;

  if (ws_size < 50331648u) return;

  char* ws = (char*)d_ws;
  unsigned short* qp   = (unsigned short*)(ws + 0);          //  8,388,608
  unsigned short* kpp  = (unsigned short*)(ws + 8388608);    //  8,388,608
  unsigned short* vtp  = (unsigned short*)(ws + 16777216);   //  8,388,608
  unsigned short* tTp  = (unsigned short*)(ws + 25165824);   // 12,582,912
  unsigned short* pwkp = (unsigned short*)(ws + 37748736);   //  3,145,728
  float*          xatt = (float*)(ws + 25165824);            //  8,388,608
  unsigned short* y1p  = (unsigned short*)(ws + 0);          // 16,777,216
  unsigned short* lwp  = (unsigned short*)(ws + 16777216);   // 33,554,432

  // split all three pointwise weight slabs in one launch: [1536][512]->[1536][1024]
  split_kernel<<<768, 256, 0, stream>>>(pwk, pwkp, 9, 196608);

  for (int i = 0; i < 3; ++i) {
    const float* x = (i == 0) ? q : (i == 1) ? k : v;
    stageA_kernel<<<1024, 256, 0, stream>>>(
        x, dwk + (size_t)i * 512 * 9, bng + i * 512, bnb + i * 512,
        bnm + i * 512, bnv + i * 512, tTp);
    unsigned short* dst = (i == 0) ? qp : (i == 1) ? kpp : vtp;
    dim3 g1(32, 8);
    gemm_split_kernel<<<g1, 256, 0, stream>>>(
        pwkp + (size_t)i * 524288, tTp, dst, 512, 4096, 512, i);
  }

  dim3 g2(8, 2, 64);
  attn_mfma_kernel<<<g2, 256, 0, stream>>>(qp, kpp, vtp, pos, xatt);

  conv1d_kernel<<<dim3(4, 64), 512, 0, stream>>>(xatt, c1w, c1b, y1p);

  split_kernel<<<8192, 256, 0, stream>>>(linw, lwp, 11, 2097152);

  dim3 g3(32, 8);   // MUST stay (32,8): swizzle hardcoded
  gemm_pipe_kernel<<<g3, 512, 0, stream>>>(y1p, lwp, out, linb, 2048, 4096, 2048);
}

// Round 7
// 217.496 us; speedup vs baseline: 3.4963x; 1.1967x over previous
//
#include <hip/hip_runtime.h>

// ---------------------------------------------------------------------------
// Geometry: b=64, units=32, d_model=4096, P=16 -> c=2, d=256, C=512,
// dwconv 3x3 s2 16x16->8x8 (hw=64), dk=64; attn 256x256 per (b,cc);
// conv1d 16->32 over l=2048; linear 2048->4096.
//
// All GEMM-shaped work runs as bf16 hi/lo split MFMA:
//   C = Ah*Bh + Ah*Bl + Al*Bh  (K' = 3K, error ~2^-17 rel).
//
// Workspace (bytes), ws >= 50331648:
//   phase1: q'  bf16 [128][256][128] @ 0           (8,388,608)
//           k'  bf16 [128][256][128] @ 8,388,608   (8,388,608)
//           vt' bf16 [128][64][512]  @ 16,777,216  (8,388,608)
//           tTp bf16 [3][4096][1024] @ 25,165,824  (25,165,824)  -> ends 48MiB
//           pwkp bf16 [3][512][1024] -> parked in d_out (dead until final GEMM)
//   phase2: xatt fp32 [64][2][256][64] @ 25,165,824 (8,388,608)
//   phase3: y1' bf16 [2048][4096]    @ 0           (16,777,216)
//           linw' bf16 [4096][4096]  @ 16,777,216  (33,554,432)
// ---------------------------------------------------------------------------

typedef short s16x8 __attribute__((ext_vector_type(8)));
typedef float f32x4 __attribute__((ext_vector_type(4)));
typedef const __attribute__((address_space(1))) void* gas_t;
typedef __attribute__((address_space(3))) void* las_t;

__device__ __forceinline__ unsigned short f2bf(float x) {
  unsigned u = __float_as_uint(x);
  unsigned r = u + 0x7fffu + ((u >> 16) & 1u);
  return (unsigned short)(r >> 16);
}
__device__ __forceinline__ float bf2f(unsigned short h) {
  return __uint_as_float((unsigned)h << 16);
}

// ======================= Stage A: patch + dwconv + BN + GELU (batched) =====
// blockIdx.y = input index i (0=q,1=k,2=v); writes tTp slab i.
__global__ __launch_bounds__(256) void stageA_kernel(
    const float* __restrict__ xq, const float* __restrict__ xk,
    const float* __restrict__ xv, const float* __restrict__ dwk,
    const float* __restrict__ bng, const float* __restrict__ bnb,
    const float* __restrict__ bnm, const float* __restrict__ bnv,
    unsigned short* __restrict__ tTp)
{
  const int i  = blockIdx.y;
  const float* x = (i == 0) ? xq : (i == 1) ? xk : xv;
  const float* dwk_i = dwk + (size_t)i * 4608;
  const int co = i * 512;
  unsigned short* out = tTp + (size_t)i * 4194304;

  const int dd = threadIdx.x;              // 0..255
  const int oh = blockIdx.x & 7;
  const int cc = (blockIdx.x >> 3) & 1;
  const int b  = blockIdx.x >> 4;
  const int ch = cc * 256 + dd;

  float r[3][16];
#pragma unroll
  for (int kh = 0; kh < 3; ++kh) {
    int ih = 2 * oh - 1 + kh;
    if (ih >= 0 && ih <= 15) {
      const float* p = x + (size_t)(b * 32 + cc * 16 + ih) * 4096 + dd * 16;
#pragma unroll
      for (int jq = 0; jq < 4; ++jq)
        *(float4*)&r[kh][jq * 4] = *(const float4*)(p + jq * 4);
    } else {
#pragma unroll
      for (int j = 0; j < 16; ++j) r[kh][j] = 0.f;
    }
  }
  float w9[9];
#pragma unroll
  for (int j = 0; j < 9; ++j) w9[j] = dwk_i[ch * 9 + j];
  const float scale = bng[co + ch] / sqrtf(bnv[co + ch] + 1e-5f);
  const float shift = bnb[co + ch] - bnm[co + ch] * scale;

#pragma unroll
  for (int ow = 0; ow < 8; ++ow) {
    float acc = 0.f;
#pragma unroll
    for (int kh = 0; kh < 3; ++kh)
#pragma unroll
      for (int kw = 0; kw < 3; ++kw) {
        int iw = 2 * ow - 1 + kw;
        if (iw >= 0 && iw <= 15) acc = fmaf(r[kh][iw], w9[kh * 3 + kw], acc);
      }
    float y = acc * scale + shift;
    y = 0.5f * y * (1.f + erff(y * 0.70710678118654752f));
    unsigned short hi = f2bf(y);
    unsigned short lo = f2bf(y - bf2f(hi));
    size_t rowb = (size_t)(b * 64 + oh * 8 + ow) * 1024;
    out[rowb + ch] = hi;
    out[rowb + 512 + ch] = lo;
  }
}

// ======================= fp32 -> bf16 hi|lo split ==========================
__global__ __launch_bounds__(256) void split_kernel(
    const float* __restrict__ src, unsigned short* __restrict__ dst,
    int kshift, int total4)
{
  int i = blockIdx.x * 256 + threadIdx.x;
  if (i >= total4) return;
  size_t i4 = (size_t)i * 4;
  int K = 1 << kshift;
  int r = (int)(i4 >> kshift);
  int c = (int)(i4 & (size_t)(K - 1));
  float4 xv = *(const float4*)(src + i4);
  unsigned short h0 = f2bf(xv.x), h1 = f2bf(xv.y), h2 = f2bf(xv.z), h3 = f2bf(xv.w);
  unsigned short l0 = f2bf(xv.x - bf2f(h0)), l1 = f2bf(xv.y - bf2f(h1));
  unsigned short l2 = f2bf(xv.z - bf2f(h2)), l3 = f2bf(xv.w - bf2f(h3));
  unsigned short* dr = dst + (size_t)r * (K * 2) + c;
  uint2 hp, lp;
  hp.x = (unsigned)h0 | ((unsigned)h1 << 16);
  hp.y = (unsigned)h2 | ((unsigned)h3 << 16);
  lp.x = (unsigned)l0 | ((unsigned)l1 << 16);
  lp.y = (unsigned)l2 | ((unsigned)l3 << 16);
  *(uint2*)dr = hp;
  *(uint2*)(dr + K) = lp;
}

// ======================= pointwise: bf16-split MFMA NT GEMM (batched z=3) ==
// BM=64 x 128 tile, 4 waves 1x4. z = input index; mode = z.
// mode 0/1 (Q/K): dst[((b*2+cc)*256 + ch%256)*128 + d (+64 lo)]
// mode 2    (V) : dst[((b*2+cc)*64 + d)*512 + ch%256 (+256 lo)]  (transposed)
__global__ __launch_bounds__(256) void gemm_split_kernel(
    const unsigned short* __restrict__ Aall, const unsigned short* __restrict__ Ball,
    unsigned short* __restrict__ Call, int M, int N, int K)
{
  __shared__ unsigned short sA[4096];    // [64][64]
  __shared__ unsigned short sB[8192];    // [128][64]
  const int t = threadIdx.x;
  const int z = blockIdx.z;              // input index == mode
  const unsigned short* A = Aall + (size_t)z * 524288;
  const unsigned short* B = Ball + (size_t)z * 4194304;
  unsigned short* Cq = Call + (size_t)z * 4194304;
  const int m0 = blockIdx.y * 64, n0 = blockIdx.x * 128;
  const int Kp = 3 * K, twoK = 2 * K, Km = K - 1;
  const int lane = t & 63;
  const int wv = t >> 6;
  const int colbase = wv * 32;
  const int h = lane & 15, g = lane >> 4;

  f32x4 acc[4][2];
#pragma unroll
  for (int mf = 0; mf < 4; ++mf)
#pragma unroll
    for (int nf = 0; nf < 2; ++nf)
      acc[mf][nf] = (f32x4){0.f, 0.f, 0.f, 0.f};

  int srow[4], sblk[4];
#pragma unroll
  for (int it = 0; it < 4; ++it) {
    int s = it * 256 + t;
    srow[it] = s >> 3;
    sblk[it] = (s & 7) ^ (srow[it] & 7);
  }
  const int ldsw = (t & 192) << 4;

  for (int k0 = 0; k0 < Kp; k0 += 64) {
    __syncthreads();
#pragma unroll
    for (int it = 0; it < 2; ++it) {
      int kp = k0 + sblk[it] * 8;
      int ac = (kp < twoK) ? (kp & Km) : (kp - K);
      const unsigned short* ga = A + (size_t)(m0 + srow[it]) * twoK + ac;
      __builtin_amdgcn_global_load_lds((gas_t)(const void*)ga,
          (las_t)(void*)((char*)sA + (it * 4096 + ldsw)), 16, 0, 0);
    }
#pragma unroll
    for (int it = 0; it < 4; ++it) {
      int kp = k0 + sblk[it] * 8;
      int bc = (kp < twoK) ? kp : (kp - twoK);
      const unsigned short* gb = B + (size_t)(n0 + srow[it]) * twoK + bc;
      __builtin_amdgcn_global_load_lds((gas_t)(const void*)gb,
          (las_t)(void*)((char*)sB + (it * 4096 + ldsw)), 16, 0, 0);
    }
    __syncthreads();

#pragma unroll
    for (int kk = 0; kk < 2; ++kk) {
      s16x8 af[4], bfr[2];
#pragma unroll
      for (int mf = 0; mf < 4; ++mf) {
        int arow = mf * 16 + h;
        int aoff = arow * 128 + (((kk * 4 + g) ^ (h & 7)) << 4);
        af[mf] = *(const s16x8*)((const char*)sA + aoff);
      }
#pragma unroll
      for (int nf = 0; nf < 2; ++nf) {
        int brow = colbase + nf * 16 + h;
        int boff = brow * 128 + (((kk * 4 + g) ^ (h & 7)) << 4);
        bfr[nf] = *(const s16x8*)((const char*)sB + boff);
      }
#pragma unroll
      for (int mf = 0; mf < 4; ++mf)
#pragma unroll
        for (int nf = 0; nf < 2; ++nf)
          acc[mf][nf] = __builtin_amdgcn_mfma_f32_16x16x32_bf16(
              af[mf], bfr[nf], acc[mf][nf], 0, 0, 0);
    }
  }

  if (z < 2) {
    // Q'/K' layout: rows = attention row index (ch%256), cols = d hi|lo
#pragma unroll
    for (int mf = 0; mf < 4; ++mf) {
      int mbase = m0 + mf * 16 + g * 4;
#pragma unroll
      for (int nf = 0; nf < 2; ++nf) {
        int n = n0 + colbase + nf * 16 + h;
        int bb = n >> 6, d = n & 63;
#pragma unroll
        for (int qq = 0; qq < 4; ++qq) {
          int m = mbase + qq;
          int cc = m >> 8;
          size_t rowb = ((size_t)(bb * 2 + cc) * 256 + (m & 255)) * 128;
          float vvv = acc[mf][nf][qq];
          unsigned short hi = f2bf(vvv);
          unsigned short lo = f2bf(vvv - bf2f(hi));
          Cq[rowb + d] = hi;
          Cq[rowb + 64 + d] = lo;
        }
      }
    }
  } else {
    // V^T layout: rows = d, cols = j hi|lo ; qq -> 4 consecutive j
#pragma unroll
    for (int mf = 0; mf < 4; ++mf) {
      int mbase = m0 + mf * 16 + g * 4;
      int cc = mbase >> 8;
      int mc = mbase & 255;
#pragma unroll
      for (int nf = 0; nf < 2; ++nf) {
        int n = n0 + colbase + nf * 16 + h;
        int bb = n >> 6, d = n & 63;
        size_t rowb = ((size_t)(bb * 2 + cc) * 64 + d) * 512;
        ushort4 hv, lv;
        float v0 = acc[mf][nf][0], v1 = acc[mf][nf][1];
        float v2 = acc[mf][nf][2], v3 = acc[mf][nf][3];
        hv.x = f2bf(v0); hv.y = f2bf(v1); hv.z = f2bf(v2); hv.w = f2bf(v3);
        lv.x = f2bf(v0 - bf2f(hv.x)); lv.y = f2bf(v1 - bf2f(hv.y));
        lv.z = f2bf(v2 - bf2f(hv.z)); lv.w = f2bf(v3 - bf2f(hv.w));
        *(ushort4*)&Cq[rowb + mc] = hv;
        *(ushort4*)&Cq[rowb + 256 + mc] = lv;
      }
    }
  }
}

// ======================= final linear: deep-pipelined split GEMM ===========
// BM=256, BN=128, BK=64, 8 waves, 3 LDS buffers, counted vmcnt(6).
// 2 phases/K-tile, 16-MFMA clusters. Grid (32, 8) ONLY (hardcoded swizzle).
__global__ __launch_bounds__(512, 2) void gemm_pipe_kernel(
    const unsigned short* __restrict__ A, const unsigned short* __restrict__ B,
    float* __restrict__ C, const float* __restrict__ bias,
    int M, int N, int K)
{
  __shared__ unsigned short lds[73728];    // 147456 B = 3 x 49152
  const int t = threadIdx.x;

  // T1: XCD chunk swizzle, 4m x 8n tiles per XCD (XCD = flat%8)
  const int flat = blockIdx.y * 32 + blockIdx.x;
  const int xcd = flat & 7;
  const int ii = flat >> 3;
  const int mt = (xcd >> 2) * 4 + (ii >> 3);
  const int ntile = (xcd & 3) * 8 + (ii & 7);
  const int m0 = mt * 256;
  const int n0 = ntile * 128;

  const int twoK = 2 * K, Km = K - 1;
  const int nt = (3 * K) >> 6;             // K-tiles (>= 3)

  const int lane = t & 63;
  const int wv = t >> 6;
  const int wm = wv & 3, wn = wv >> 2;
  const int h = lane & 15, g = lane >> 4;

  f32x4 acc[4][4];
#pragma unroll
  for (int mf = 0; mf < 4; ++mf)
#pragma unroll
    for (int nf = 0; nf < 4; ++nf)
      acc[mf][nf] = (f32x4){0.f, 0.f, 0.f, 0.f};

  int arow[4], ablk[4], brow[2], bblk[2];
#pragma unroll
  for (int it = 0; it < 4; ++it) {
    int s = it * 512 + t;
    arow[it] = s >> 3;
    ablk[it] = (t & 7) ^ (arow[it] & 7);
  }
#pragma unroll
  for (int it = 0; it < 2; ++it) {
    int s = it * 512 + t;
    brow[it] = s >> 3;
    bblk[it] = (t & 7) ^ (brow[it] & 7);
  }

  auto issueA = [&](int buf, int tt, int it) {
    int kp = tt * 64 + ablk[it] * 8;
    int ac = (kp < twoK) ? (kp & Km) : (kp - K);
    __builtin_amdgcn_global_load_lds(
        (gas_t)(const void*)(A + (size_t)(m0 + arow[it]) * twoK + ac),
        (las_t)(void*)((char*)lds + (buf * 49152 + it * 8192 + t * 16)), 16, 0, 0);
  };
  auto issueB = [&](int buf, int tt, int it) {
    int kp = tt * 64 + bblk[it] * 8;
    int bc = (kp < twoK) ? kp : (kp - twoK);
    __builtin_amdgcn_global_load_lds(
        (gas_t)(const void*)(B + (size_t)(n0 + brow[it]) * twoK + bc),
        (las_t)(void*)((char*)lds + (buf * 49152 + 32768 + it * 8192 + t * 16)), 16, 0, 0);
  };

  const int aoffb = (wm * 64 + h) * 128;
  const int boffb = 32768 + (wn * 64 + h) * 128;
  int colx[2];
  colx[0] = ((g) ^ (h & 7)) << 4;
  colx[1] = ((4 + g) ^ (h & 7)) << 4;

  auto rdA = [&](int buf, int kk, int mf) -> s16x8 {
    return *(const s16x8*)((const char*)lds + (buf * 49152 + aoffb + mf * 2048 + colx[kk]));
  };
  auto rdB = [&](int buf, int kk, int nf) -> s16x8 {
    return *(const s16x8*)((const char*)lds + (buf * 49152 + boffb + nf * 2048 + colx[kk]));
  };

#define MFMA_ROW2(A0, A1, A2, A3, BB, NF) \
  acc[0][NF] = __builtin_amdgcn_mfma_f32_16x16x32_bf16(A0, BB, acc[0][NF], 0, 0, 0); \
  acc[1][NF] = __builtin_amdgcn_mfma_f32_16x16x32_bf16(A1, BB, acc[1][NF], 0, 0, 0); \
  acc[2][NF] = __builtin_amdgcn_mfma_f32_16x16x32_bf16(A2, BB, acc[2][NF], 0, 0, 0); \
  acc[3][NF] = __builtin_amdgcn_mfma_f32_16x16x32_bf16(A3, BB, acc[3][NF], 0, 0, 0);

  // ---- prologue: stage tiles 0 and 1 ----
#pragma unroll
  for (int it = 0; it < 4; ++it) issueA(0, 0, it);
#pragma unroll
  for (int it = 0; it < 2; ++it) issueB(0, 0, it);
#pragma unroll
  for (int it = 0; it < 4; ++it) issueA(1, 1, it);
#pragma unroll
  for (int it = 0; it < 2; ++it) issueB(1, 1, it);
  asm volatile("s_waitcnt vmcnt(6)" ::: "memory");
  __builtin_amdgcn_sched_barrier(0);
  __builtin_amdgcn_s_barrier();
  __builtin_amdgcn_sched_barrier(0);

  int bR = 0;
  for (int tt = 0; tt <= nt - 3; ++tt) {
    const int bn2 = (bR >= 1) ? bR - 1 : 2;      // (bR+2)%3
    // ---- phase 0: kk=0 frags (8 ds_read); prefetch A slices 0..3 ----
    s16x8 a0 = rdA(bR, 0, 0), a1 = rdA(bR, 0, 1), a2 = rdA(bR, 0, 2), a3 = rdA(bR, 0, 3);
    s16x8 b0 = rdB(bR, 0, 0), b1 = rdB(bR, 0, 1), b2 = rdB(bR, 0, 2), b3 = rdB(bR, 0, 3);
    issueA(bn2, tt + 2, 0); issueA(bn2, tt + 2, 1);
    issueA(bn2, tt + 2, 2); issueA(bn2, tt + 2, 3);
    __builtin_amdgcn_s_barrier();
    __builtin_amdgcn_s_setprio(1);
    MFMA_ROW2(a0, a1, a2, a3, b0, 0)
    MFMA_ROW2(a0, a1, a2, a3, b1, 1)
    MFMA_ROW2(a0, a1, a2, a3, b2, 2)
    MFMA_ROW2(a0, a1, a2, a3, b3, 3)
    __builtin_amdgcn_s_setprio(0);
    __builtin_amdgcn_s_barrier();
    // ---- phase 1: kk=1 frags; prefetch B slices; counted vmcnt; publish ----
    a0 = rdA(bR, 1, 0); a1 = rdA(bR, 1, 1); a2 = rdA(bR, 1, 2); a3 = rdA(bR, 1, 3);
    b0 = rdB(bR, 1, 0); b1 = rdB(bR, 1, 1); b2 = rdB(bR, 1, 2); b3 = rdB(bR, 1, 3);
    issueB(bn2, tt + 2, 0); issueB(bn2, tt + 2, 1);
    __builtin_amdgcn_s_barrier();
    __builtin_amdgcn_s_setprio(1);
    MFMA_ROW2(a0, a1, a2, a3, b0, 0)
    MFMA_ROW2(a0, a1, a2, a3, b1, 1)
    MFMA_ROW2(a0, a1, a2, a3, b2, 2)
    MFMA_ROW2(a0, a1, a2, a3, b3, 3)
    __builtin_amdgcn_s_setprio(0);
    asm volatile("s_waitcnt vmcnt(6)" ::: "memory");
    __builtin_amdgcn_sched_barrier(0);
    __builtin_amdgcn_s_barrier();
    __builtin_amdgcn_sched_barrier(0);
    bR = (bR == 2) ? 0 : bR + 1;
  }

  auto compute_tile = [&](int buf) {
#pragma unroll
    for (int kk = 0; kk < 2; ++kk) {
      s16x8 ta0 = rdA(buf, kk, 0), ta1 = rdA(buf, kk, 1);
      s16x8 ta2 = rdA(buf, kk, 2), ta3 = rdA(buf, kk, 3);
      s16x8 tb0 = rdB(buf, kk, 0), tb1 = rdB(buf, kk, 1);
      s16x8 tb2 = rdB(buf, kk, 2), tb3 = rdB(buf, kk, 3);
      MFMA_ROW2(ta0, ta1, ta2, ta3, tb0, 0)
      MFMA_ROW2(ta0, ta1, ta2, ta3, tb1, 1)
      MFMA_ROW2(ta0, ta1, ta2, ta3, tb2, 2)
      MFMA_ROW2(ta0, ta1, ta2, ta3, tb3, 3)
    }
  };
  compute_tile(bR);
  __syncthreads();
  compute_tile((bR == 2) ? 0 : bR + 1);
#undef MFMA_ROW2

#pragma unroll
  for (int mf = 0; mf < 4; ++mf) {
    int mbase = m0 + wm * 64 + mf * 16 + g * 4;
#pragma unroll
    for (int nf = 0; nf < 4; ++nf) {
      int n = n0 + wn * 64 + nf * 16 + h;
      float bv = bias[n];
#pragma unroll
      for (int qq = 0; qq < 4; ++qq)
        C[(size_t)(mbase + qq) * N + n] = acc[mf][nf][qq] + bv;
    }
  }
}

// ======================= Attention (MFMA, split bf16) ======================
__global__ __launch_bounds__(256) void attn_mfma_kernel(
    const unsigned short* __restrict__ qp, const unsigned short* __restrict__ kp,
    const unsigned short* __restrict__ vtp, const float* __restrict__ pos,
    float* __restrict__ xatt)
{
  __shared__ char smem[59904];
  unsigned short* qs = (unsigned short*)smem;
  unsigned short* kv = (unsigned short*)(smem + 8704);
  float* sc = (float*)(smem + 26112);
  unsigned short* ps = (unsigned short*)(smem + 26112);

  const int t = threadIdx.x;
  const int rt = blockIdx.x, cc = blockIdx.y, b = blockIdx.z;
  const int i0 = rt * 32;
  const size_t qkbase = (size_t)(b * 2 + cc) * 256;
  const size_t vbase  = (size_t)(b * 2 + cc) * 64;

  const int lane = t & 63, wvv = t >> 6;
  const int h = lane & 15, g = lane >> 4;

  // ---- stage Q tile (32 rows x 128 split cols = 512 int4, 2 passes) ----
#pragma unroll
  for (int rep = 0; rep < 2; ++rep) {
    int s = t + rep * 256;
    int row = s >> 4;
    int blk = s & 15;
    int4 val = *(const int4*)(qp + (qkbase + i0 + row) * 128 + blk * 8);
    *(int4*)((char*)qs + row * 272 + blk * 16) = val;
  }

  // ---- S phase: 4 chunks of 64 cols ----
  for (int c = 0; c < 4; ++c) {
    __syncthreads();
#pragma unroll
    for (int p2 = 0; p2 < 4; ++p2) {
      int s = t + p2 * 256;
      int row = s >> 4;
      int blk = s & 15;
      int4 val = *(const int4*)(kp + (qkbase + c * 64 + row) * 128 + blk * 8);
      *(int4*)((char*)kv + row * 272 + blk * 16) = val;
    }
    __syncthreads();
    f32x4 acc2[2];
    acc2[0] = (f32x4){0.f, 0.f, 0.f, 0.f};
    acc2[1] = (f32x4){0.f, 0.f, 0.f, 0.f};
#pragma unroll
    for (int kk = 0; kk < 6; ++kk) {
      int abase = (kk < 2) ? kk * 32 : (kk < 4) ? 64 + (kk - 2) * 32 : (kk - 4) * 32;
      int bbase = (kk < 2) ? kk * 32 : (kk < 4) ? (kk - 2) * 32 : 64 + (kk - 4) * 32;
      s16x8 bfrag = *(const s16x8*)((char*)kv + (wvv * 16 + h) * 272 + (bbase + g * 8) * 2);
#pragma unroll
      for (int mf = 0; mf < 2; ++mf) {
        s16x8 afrag = *(const s16x8*)((char*)qs + (mf * 16 + h) * 272 + (abase + g * 8) * 2);
        acc2[mf] = __builtin_amdgcn_mfma_f32_16x16x32_bf16(afrag, bfrag, acc2[mf], 0, 0, 0);
      }
    }
#pragma unroll
    for (int mf = 0; mf < 2; ++mf)
#pragma unroll
      for (int qq = 0; qq < 4; ++qq) {
        int row = mf * 16 + g * 4 + qq;
        int j = c * 64 + wvv * 16 + h;
        sc[row * 264 + j] = acc2[mf][qq] * 0.125f +
            pos[((size_t)cc * 256 + i0 + row) * 256 + j];
      }
  }
  __syncthreads();

  // ---- softmax (fp32, 8 threads/row) + in-place P split-bf16 write ----
  {
    const int r = t >> 3, j8 = t & 7;
    float e[32];
    float mx = -3.4e38f;
#pragma unroll
    for (int jj = 0; jj < 32; ++jj) {
      e[jj] = sc[r * 264 + j8 + 8 * jj];
      mx = fmaxf(mx, e[jj]);
    }
#pragma unroll
    for (int mset = 1; mset < 8; mset <<= 1) mx = fmaxf(mx, __shfl_xor(mx, mset, 64));
    float sum = 0.f;
#pragma unroll
    for (int jj = 0; jj < 32; ++jj) {
      e[jj] = expf(e[jj] - mx);
      sum += e[jj];
    }
#pragma unroll
    for (int mset = 1; mset < 8; mset <<= 1) sum += __shfl_xor(sum, mset, 64);
    float inv = 1.f / sum;
    __syncthreads();
#pragma unroll
    for (int jj = 0; jj < 32; ++jj) {
      float pv = e[jj] * inv;
      unsigned short hi = f2bf(pv);
      unsigned short lo = f2bf(pv - bf2f(hi));
      int j = j8 + 8 * jj;
      ps[r * 528 + j] = hi;
      ps[r * 528 + 264 + j] = lo;
    }
  }

  // ---- PV: O[32][64] += P[32][j-chunk] * Vt[d][j-chunk] ----
  f32x4 oacc[2];
  oacc[0] = (f32x4){0.f, 0.f, 0.f, 0.f};
  oacc[1] = (f32x4){0.f, 0.f, 0.f, 0.f};
  for (int c = 0; c < 4; ++c) {
    __syncthreads();
#pragma unroll
    for (int p2 = 0; p2 < 4; ++p2) {
      int s = t + p2 * 256, row = s >> 4, blk = s & 15;
      int col = (blk < 8) ? (c * 64 + blk * 8) : (256 + c * 64 + (blk - 8) * 8);
      int4 val = *(const int4*)(vtp + (vbase + row) * 512 + col);
      *(int4*)((char*)kv + row * 272 + blk * 16) = val;
    }
    __syncthreads();
#pragma unroll
    for (int kk = 0; kk < 6; ++kk) {
      int abase = (kk < 2) ? (c * 64 + kk * 32)
                : (kk < 4) ? (264 + c * 64 + (kk - 2) * 32)
                           : (c * 64 + (kk - 4) * 32);
      int bbase = (kk < 2) ? kk * 32 : (kk < 4) ? (kk - 2) * 32 : 64 + (kk - 4) * 32;
      s16x8 bfrag = *(const s16x8*)((char*)kv + (wvv * 16 + h) * 272 + (bbase + g * 8) * 2);
#pragma unroll
      for (int mf = 0; mf < 2; ++mf) {
        s16x8 afrag = *(const s16x8*)((char*)ps + (mf * 16 + h) * 1056 + (abase + g * 8) * 2);
        oacc[mf] = __builtin_amdgcn_mfma_f32_16x16x32_bf16(afrag, bfrag, oacc[mf], 0, 0, 0);
      }
    }
  }
#pragma unroll
  for (int mf = 0; mf < 2; ++mf)
#pragma unroll
    for (int qq = 0; qq < 4; ++qq) {
      int row = mf * 16 + g * 4 + qq;
      int d = wvv * 16 + h;
      xatt[((size_t)(b * 2 + cc) * 256 + i0 + row) * 64 + d] = oacc[mf][qq];
    }
}

// ======================= rearrange + conv1d -> y1' bf16 hi|lo ==============
__global__ __launch_bounds__(512) void conv1d_kernel(
    const float* __restrict__ xatt, const float* __restrict__ w,
    const float* __restrict__ bias, unsigned short* __restrict__ y1p)
{
  __shared__ float X[16][520];
  __shared__ float W[512];
  __shared__ float Bp[32];
  const int t = threadIdx.x;       // 0..511
  const int lt = blockIdx.x;       // 0..3
  const int b  = blockIdx.y;       // 0..63
  if (t < 512) W[t] = w[t];
  if (t < 32) Bp[t] = bias[t];
#pragma unroll
  for (int cc = 0; cc < 2; ++cc) {
    const float* src = xatt + ((size_t)(b * 2 + cc) * 256 + lt * 64) * 64;
#pragma unroll
    for (int pass = 0; pass < 2; ++pass) {
      int f4 = t + pass * 512;
      float4 v4 = *(const float4*)(src + (size_t)f4 * 4);
      int fl = f4 * 4;
      int dl = fl >> 6;
      int rr = fl & 63;
      int p1 = rr >> 3, p2 = rr & 7;
      *(float4*)&X[cc * 8 + p1][dl * 8 + p2] = v4;
    }
  }
  __syncthreads();

  float xv[16];
#pragma unroll
  for (int ch = 0; ch < 16; ++ch) xv[ch] = X[ch][t];

  size_t obase = (size_t)b * 32 * 4096 + lt * 512 + t;
#pragma unroll
  for (int o = 0; o < 32; ++o) {
    float s = Bp[o];
#pragma unroll
    for (int ch = 0; ch < 16; ++ch) s = fmaf(xv[ch], W[o * 16 + ch], s);
    unsigned short hi = f2bf(s);
    unsigned short lo = f2bf(s - bf2f(hi));
    y1p[obase + (size_t)o * 4096] = hi;
    y1p[obase + (size_t)o * 4096 + 2048] = lo;
  }
}

// ======================= launch ============================================
extern "C" void kernel_launch(void* const* d_in, const int* in_sizes, int n_in,
                              void* d_out, int out_size, void* d_ws, size_t ws_size,
                              hipStream_t stream) {
  const float* q    = (const float*)d_in[0];
  const float* k    = (const float*)d_in[1];
  const float* v    = (const float*)d_in[2];
  const float* dwk  = (const float*)d_in[3];
  const float* bng  = (const float*)d_in[4];
  const float* bnb  = (const float*)d_in[5];
  const float* bnm  = (const float*)d_in[6];
  const float* bnv  = (const float*)d_in[7];
  const float* pwk  = (const float*)d_in[8];
  const float* pos  = (const float*)d_in[9];
  const float* c1w  = (const float*)d_in[10];
  const float* c1b  = (const float*)d_in[11];
  const float* linw = (const float*)d_in[12];
  const float* linb = (const float*)d_in[13];
  float* out = (float*)d_out;

  if (ws_size < 50331648u) return;

  char* ws = (char*)d_ws;
  unsigned short* qp   = (unsigned short*)(ws + 0);          //  8,388,608
  unsigned short* kpp  = (unsigned short*)(ws + 8388608);    //  8,388,608
  unsigned short* vtp  = (unsigned short*)(ws + 16777216);   //  8,388,608
  unsigned short* tTp  = (unsigned short*)(ws + 25165824);   // 25,165,824 (3 slabs)
  unsigned short* pwkp = (unsigned short*)d_out;             //  3,145,728 (scratch in out)
  float*          xatt = (float*)(ws + 25165824);            //  8,388,608
  unsigned short* y1p  = (unsigned short*)(ws + 0);          // 16,777,216
  unsigned short* lwp  = (unsigned short*)(ws + 16777216);   // 33,554,432

  // split all three pointwise weight slabs (into d_out scratch)
  split_kernel<<<768, 256, 0, stream>>>(pwk, pwkp, 9, 196608);

  // all three dwconv+BN+GELU stages in one launch
  stageA_kernel<<<dim3(1024, 3), 256, 0, stream>>>(
      q, k, v, dwk, bng, bnb, bnm, bnv, tTp);

  // all three pointwise GEMMs in one launch (z = input index)
  gemm_split_kernel<<<dim3(32, 8, 3), 256, 0, stream>>>(
      pwkp, tTp, qp, 512, 4096, 512);

  dim3 g2(8, 2, 64);
  attn_mfma_kernel<<<g2, 256, 0, stream>>>(qp, kpp, vtp, pos, xatt);

  conv1d_kernel<<<dim3(4, 64), 512, 0, stream>>>(xatt, c1w, c1b, y1p);

  split_kernel<<<8192, 256, 0, stream>>>(linw, lwp, 11, 2097152);

  dim3 g3(32, 8);   // MUST stay (32,8): swizzle hardcoded
  gemm_pipe_kernel<<<g3, 512, 0, stream>>>(y1p, lwp, out, linb, 2048, 4096, 2048);
}